// Round 1
// baseline (571.745 us; speedup 1.0000x reference)
//
#include <hip/hip_runtime.h>
#include <hip/hip_bf16.h>

#define NEDGE 320000
#define NNODE 20000
#define MP    20096      // 157*128 padded rows
#define NRELS 8
#define NSEG  (NNODE*NRELS)   // 160000
#define FEAT  128
#define HID   256
#define EMB   128
#define NGRAPH 20
#define NPG   1000

typedef __attribute__((ext_vector_type(4))) float f32x4;
typedef __attribute__((ext_vector_type(8))) __bf16 bf16x8;

static __device__ __forceinline__ float bf2f(unsigned short u){
  union { unsigned int i; float f; } v; v.i = ((unsigned int)u) << 16; return v.f;
}
static __device__ __forceinline__ unsigned short f2bf(float f){
  union { float f; unsigned int i; } v; v.f = f;
  unsigned int x = v.i;
  return (unsigned short)((x + 0x7fffu + ((x >> 16) & 1u)) >> 16);
}

__device__ __forceinline__ void load_lds16(const void* g, void* l){
  __builtin_amdgcn_global_load_lds((const __attribute__((address_space(1))) void*)g,
                                   (__attribute__((address_space(3))) void*)l, 16, 0, 0);
}

// ---------------- edge preprocessing ----------------
__global__ void k_hist(const int* __restrict__ ei, const int* __restrict__ et, int* __restrict__ cnt){
  int e = blockIdx.x*256 + threadIdx.x;
  if (e < NEDGE){
    int key = ei[NEDGE + e]*NRELS + et[e];
    atomicAdd(&cnt[key], 1);
  }
}

__global__ void k_scan(const int* __restrict__ cnt, int* __restrict__ offs){
  __shared__ int sb[1024];
  const int t = threadIdx.x;
  const int PT = 157; // 1024*157 >= 160000
  int base = t*PT;
  int s = 0;
  for (int j=0;j<PT;j++){ int i = base+j; if (i < NSEG) s += cnt[i]; }
  sb[t] = s; __syncthreads();
  for (int off=1; off<1024; off<<=1){
    int v = (t >= off) ? sb[t-off] : 0;
    __syncthreads();
    sb[t] += v;
    __syncthreads();
  }
  int run = sb[t] - s;  // exclusive prefix
  for (int j=0;j<PT;j++){ int i = base+j; if (i < NSEG){ offs[i] = run; run += cnt[i]; } }
}

__global__ void k_scatter(const int* __restrict__ ei, const int* __restrict__ et,
                          const int* __restrict__ offs, int* __restrict__ cursor, int* __restrict__ ssrc){
  int e = blockIdx.x*256 + threadIdx.x;
  if (e < NEDGE){
    int src = ei[e];
    int key = ei[NEDGE + e]*NRELS + et[e];
    int pos = offs[key] + atomicAdd(&cursor[key], 1);
    ssrc[pos] = src;
  }
}

// ---------------- segment means ----------------
// layer1: mean of node_x[src] (f32, 128 wide) per (dst,rel) -> s1 bf16 [MP][1024]
__global__ void k_agg1(const float* __restrict__ xin, const int* __restrict__ offs,
                       const int* __restrict__ cnt, const int* __restrict__ ssrc,
                       unsigned short* __restrict__ s1){
  int w = threadIdx.x >> 6, lane = threadIdx.x & 63;
  int seg = blockIdx.x*4 + w;
  if (seg >= NSEG) return;
  int c = cnt[seg], o = offs[seg];
  float a0 = 0.f, a1 = 0.f;
  for (int j=0;j<c;j++){
    int s = ssrc[o+j];
    float2 v = *(const float2*)(xin + (size_t)s*FEAT + lane*2);
    a0 += v.x; a1 += v.y;
  }
  float inv = (c > 0) ? 1.f/(float)c : 0.f;
  int n = seg >> 3, r = seg & 7;
  unsigned int pack = (unsigned int)f2bf(a0*inv) | ((unsigned int)f2bf(a1*inv) << 16);
  *(unsigned int*)(s1 + (size_t)n*1024 + r*FEAT + lane*2) = pack;
}

// layer2: mean of h[src] (bf16, 256 wide) per (dst,rel) -> s2 bf16 [MP][2048]
__global__ void k_agg2(const unsigned short* __restrict__ h, const int* __restrict__ offs,
                       const int* __restrict__ cnt, const int* __restrict__ ssrc,
                       unsigned short* __restrict__ s2){
  int w = threadIdx.x >> 6, lane = threadIdx.x & 63;
  int seg = blockIdx.x*4 + w;
  if (seg >= NSEG) return;
  int c = cnt[seg], o = offs[seg];
  float a0=0.f, a1=0.f, a2=0.f, a3=0.f;
  for (int j=0;j<c;j++){
    int s = ssrc[o+j];
    ushort4 v = *(const ushort4*)(h + (size_t)s*HID + lane*4);
    a0 += bf2f(v.x); a1 += bf2f(v.y); a2 += bf2f(v.z); a3 += bf2f(v.w);
  }
  float inv = (c > 0) ? 1.f/(float)c : 0.f;
  int n = seg >> 3, r = seg & 7;
  ushort4 out;
  out.x = f2bf(a0*inv); out.y = f2bf(a1*inv); out.z = f2bf(a2*inv); out.w = f2bf(a3*inv);
  *(ushort4*)(s2 + (size_t)n*2048 + r*HID + lane*4) = out;
}

// ---------------- weight prep ----------------
__global__ void k_cvt_nodex(const float* __restrict__ xin, unsigned short* __restrict__ xb){
  int i = blockIdx.x*256 + threadIdx.x;
  if (i < NNODE*FEAT) xb[i] = f2bf(xin[i]);
}

// B1t: [256][1152] bf16, row o: k<1024 -> W1[r=k>>7][i=k&127][o], else root1[k-1024][o]
__global__ void k_genB1(const float* __restrict__ comp, const float* __restrict__ basis,
                        const float* __restrict__ root, unsigned short* __restrict__ Bt){
  int idx = blockIdx.x*256 + threadIdx.x;
  if (idx >= 256*1152) return;
  int o = idx / 1152, k = idx % 1152;
  float v;
  if (k < 1024){
    int r = k >> 7, i = k & 127;
    v = 0.f;
    for (int b=0;b<4;b++) v += comp[r*4+b] * basis[((b*128)+i)*256 + o];
  } else {
    v = root[(k-1024)*256 + o];
  }
  Bt[(size_t)o*1152 + k] = f2bf(v);
}

// B2t: [128][2304] bf16
__global__ void k_genB2(const float* __restrict__ comp, const float* __restrict__ basis,
                        const float* __restrict__ root, unsigned short* __restrict__ Bt){
  int idx = blockIdx.x*256 + threadIdx.x;
  if (idx >= 128*2304) return;
  int o = idx / 2304, k = idx % 2304;
  float v;
  if (k < 2048){
    int r = k >> 8, i = k & 255;
    v = 0.f;
    for (int b=0;b<4;b++) v += comp[r*4+b] * basis[((b*256)+i)*128 + o];
  } else {
    v = root[(k-2048)*128 + o];
  }
  Bt[(size_t)o*2304 + k] = f2bf(v);
}

// ---------------- GEMM: C[M x 128tile] = [A0|A1] @ Bt^T ----------------
// A split in K: first K0 cols from A0 (ld ldA0), rest from A1 (ld ldA1). Bt is N x K row-major.
// LDS tiles staged via global_load_lds w/ XOR-swizzled source (slot ^= row&7) so ds_read_b128 is ~2-way.
template<int BM, bool RELU>
__global__ __launch_bounds__(256, 2)
void k_gemm(const unsigned short* __restrict__ A0, int ldA0,
            const unsigned short* __restrict__ A1, int ldA1, int K0, int K,
            const unsigned short* __restrict__ Bt,
            const float* __restrict__ bias,
            unsigned short* __restrict__ Cb, float* __restrict__ Cf, int ldC)
{
  constexpr int BK = 64;
  constexpr int FM = BM/32;          // 16x16 m-frags per wave (2 wave-rows)
  constexpr int TA = BM*8/256;       // 16B chunks per thread for A tile
  __shared__ __align__(16) unsigned short As[BM*BK];
  __shared__ __align__(16) unsigned short Bs[128*BK];

  const int tid  = threadIdx.x;
  const int w    = tid >> 6, lane = tid & 63;
  const int wr   = w >> 1,  wc   = w & 1;
  const int m0   = blockIdx.x * BM;
  const int n0   = blockIdx.y * 128;

  const f32x4 zero4 = {0.f,0.f,0.f,0.f};
  f32x4 acc[FM][4];
  for (int i=0;i<FM;i++) for (int j=0;j<4;j++) acc[i][j] = zero4;

  const int nkt = K / BK;
  for (int kt=0; kt<nkt; ++kt){
    const int kb = kt*BK;
    // stage A (pre-swizzled source -> linear LDS)
    {
      const unsigned short* Ab; int ld, kk;
      if (kb < K0){ Ab = A0; ld = ldA0; kk = kb; } else { Ab = A1; ld = ldA1; kk = kb - K0; }
      #pragma unroll
      for (int t=0;t<TA;t++){
        int c = t*256 + tid;
        int row = c >> 3, slot = c & 7;
        int srcs = slot ^ (row & 7);
        const unsigned short* g = Ab + (size_t)(m0+row)*ld + kk + srcs*8;
        load_lds16(g, (char*)As + (t*256 + w*64)*16);
      }
    }
    // stage B
    {
      #pragma unroll
      for (int t=0;t<4;t++){
        int c = t*256 + tid;
        int row = c >> 3, slot = c & 7;
        int srcs = slot ^ (row & 7);
        const unsigned short* g = Bt + (size_t)(n0+row)*K + kb + srcs*8;
        load_lds16(g, (char*)Bs + (t*256 + w*64)*16);
      }
    }
    asm volatile("s_waitcnt vmcnt(0)" ::: "memory");
    __syncthreads();
    // compute
    #pragma unroll
    for (int kk=0; kk<2; ++kk){
      bf16x8 bfr[4];
      #pragma unroll
      for (int fn=0; fn<4; ++fn){
        int row  = wc*64 + fn*16 + (lane & 15);
        int slot = (kk*4 + (lane >> 4)) ^ (row & 7);
        bfr[fn] = *(const bf16x8*)(Bs + row*64 + slot*8);
      }
      #pragma unroll
      for (int fm=0; fm<FM; ++fm){
        int row  = wr*(BM/2) + fm*16 + (lane & 15);
        int slot = (kk*4 + (lane >> 4)) ^ (row & 7);
        bf16x8 afr = *(const bf16x8*)(As + row*64 + slot*8);
        #pragma unroll
        for (int fn=0; fn<4; ++fn){
          acc[fm][fn] = __builtin_amdgcn_mfma_f32_16x16x32_bf16(afr, bfr[fn], acc[fm][fn], 0, 0, 0);
        }
      }
    }
    __syncthreads();
  }
  // epilogue: C/D layout col=lane&15, row=(lane>>4)*4+q  (outputs padded to MP rows -> no guards)
  #pragma unroll
  for (int fm=0; fm<FM; ++fm){
    int rbase = m0 + wr*(BM/2) + fm*16 + (lane >> 4)*4;
    #pragma unroll
    for (int fn=0; fn<4; ++fn){
      int col = n0 + wc*64 + fn*16 + (lane & 15);
      float b = bias[col];
      #pragma unroll
      for (int q=0;q<4;q++){
        float v = acc[fm][fn][q] + b;
        int row = rbase + q;
        if constexpr (RELU){
          v = v > 0.f ? v : 0.f;
          Cb[(size_t)row*ldC + col] = f2bf(v);
        } else {
          Cf[(size_t)row*ldC + col] = v;
        }
      }
    }
  }
}

// ---------------- head ----------------
__global__ void k_me(const float* __restrict__ x, const float* __restrict__ mw,
                     const float* __restrict__ mb, float* __restrict__ me){
  int id = blockIdx.x*256 + threadIdx.x;
  if (id >= NGRAPH*EMB) return;
  int g = id >> 7, e = id & 127;
  float s = mb[e];
  for (int i=0;i<HID;i++) s += x[g*HID + i] * mw[i*EMB + e];
  me[id] = s;
}

__global__ void k_scores(const float* __restrict__ nemb, const float* __restrict__ me,
                         const int* __restrict__ batch, float* __restrict__ sc){
  int w = threadIdx.x >> 6, lane = threadIdx.x & 63;
  int n = blockIdx.x*4 + w;
  if (n >= NNODE) return;
  int g = batch[n];
  float2 v = *(const float2*)(nemb + (size_t)n*EMB + lane*2);
  float2 m = *(const float2*)(me + g*EMB + lane*2);
  float p = v.x*m.x + v.y*m.y;
  for (int d=32; d; d>>=1) p += __shfl_down(p, d);
  if (lane == 0) sc[n] = p;
}

__global__ void k_lsm(const float* __restrict__ sc, float* __restrict__ out){
  __shared__ float sb[1024];
  __shared__ float red[256];
  int g = blockIdx.x, t = threadIdx.x;
  float lm = -1e30f;
  for (int j=t; j<1024; j+=256){
    float v = (j < NPG) ? sc[g*NPG + j] : -1e30f;
    sb[j] = v; lm = fmaxf(lm, v);
  }
  red[t] = lm; __syncthreads();
  for (int off=128; off; off>>=1){ if (t < off) red[t] = fmaxf(red[t], red[t+off]); __syncthreads(); }
  float mx = red[0]; __syncthreads();
  float ls = 0.f;
  for (int j=t; j<1024; j+=256){ if (j < NPG) ls += expf(sb[j] - mx); }
  red[t] = ls; __syncthreads();
  for (int off=128; off; off>>=1){ if (t < off) red[t] += red[t+off]; __syncthreads(); }
  float lse = mx + logf(red[0]);
  for (int j=t; j<NPG; j+=256) out[g*NPG + j] = sb[j] - lse;
}

// ---------------- launch ----------------
extern "C" void kernel_launch(void* const* d_in, const int* in_sizes, int n_in,
                              void* d_out, int out_size, void* d_ws, size_t ws_size,
                              hipStream_t stream) {
  const float* x       = (const float*)d_in[0];
  const float* node_x  = (const float*)d_in[2];
  const int*   ei      = (const int*)d_in[3];
  const int*   et      = (const int*)d_in[4];
  const int*   batch   = (const int*)d_in[5];
  const float* comp1   = (const float*)d_in[7];
  const float* basis1  = (const float*)d_in[8];
  const float* root1   = (const float*)d_in[9];
  const float* bias1   = (const float*)d_in[10];
  const float* comp2   = (const float*)d_in[11];
  const float* basis2  = (const float*)d_in[12];
  const float* root2   = (const float*)d_in[13];
  const float* bias2   = (const float*)d_in[14];
  const float* msg_w   = (const float*)d_in[15];
  const float* msg_b   = (const float*)d_in[16];
  float* out = (float*)d_out;

  char* p = (char*)d_ws;
  size_t off = 0;
  auto alloc = [&](size_t bytes) -> char* {
    char* r = p + off;
    off += (bytes + 255) & ~(size_t)255;
    return r;
  };
  int*            cnt    = (int*)alloc(NSEG*4);
  int*            offs   = (int*)alloc(NSEG*4);
  int*            cursor = (int*)alloc(NSEG*4);
  int*            ssrc   = (int*)alloc(NEDGE*4);
  unsigned short* B1t    = (unsigned short*)alloc((size_t)256*1152*2);
  unsigned short* B2t    = (unsigned short*)alloc((size_t)128*2304*2);
  float*          me     = (float*)alloc(NGRAPH*EMB*4);
  unsigned short* xb     = (unsigned short*)alloc((size_t)MP*FEAT*2);
  unsigned short* s1     = (unsigned short*)alloc((size_t)MP*1024*2);
  unsigned short* h      = (unsigned short*)alloc((size_t)MP*HID*2);
  unsigned short* s2     = (unsigned short*)alloc((size_t)MP*2048*2);
  float*          nemb   = (float*)alloc((size_t)MP*EMB*4);
  float*          sc     = (float*)alloc(NNODE*4);

  hipMemsetAsync(cnt,    0, NSEG*4, stream);
  hipMemsetAsync(cursor, 0, NSEG*4, stream);

  k_hist   <<<1250, 256, 0, stream>>>(ei, et, cnt);
  k_scan   <<<1, 1024, 0, stream>>>(cnt, offs);
  k_scatter<<<1250, 256, 0, stream>>>(ei, et, offs, cursor, ssrc);

  k_cvt_nodex<<<10000, 256, 0, stream>>>(node_x, xb);
  k_genB1<<<1152, 256, 0, stream>>>(comp1, basis1, root1, B1t);
  k_genB2<<<1152, 256, 0, stream>>>(comp2, basis2, root2, B2t);
  k_me   <<<10, 256, 0, stream>>>(x, msg_w, msg_b, me);

  k_agg1<<<40000, 256, 0, stream>>>(node_x, offs, cnt, ssrc, s1);
  k_gemm<64, true><<<dim3(MP/64, 2), 256, 0, stream>>>(s1, 1024, xb, FEAT, 1024, 1152,
                                                       B1t, bias1, h, nullptr, HID);
  k_agg2<<<40000, 256, 0, stream>>>(h, offs, cnt, ssrc, s2);
  k_gemm<64, false><<<dim3(MP/64, 1), 256, 0, stream>>>(s2, 2048, h, HID, 2048, 2304,
                                                        B2t, bias2, nullptr, nemb, EMB);

  k_scores<<<5000, 256, 0, stream>>>(nemb, me, batch, sc);
  k_lsm   <<<NGRAPH, 256, 0, stream>>>(sc, out);
}

// Round 2
// 281.261 us; speedup vs baseline: 2.0328x; 2.0328x over previous
//
#include <hip/hip_runtime.h>
#include <hip/hip_bf16.h>

#define NEDGE 320000
#define NNODE 20000
#define MP    20096      // 157*128 padded rows
#define NRELS 8
#define NSEG  (NNODE*NRELS)   // 160000
#define FEAT  128
#define HID   256
#define EMB   128
#define NGRAPH 20
#define NPG   1000

typedef __attribute__((ext_vector_type(4))) float f32x4;
typedef __attribute__((ext_vector_type(8))) __bf16 bf16x8;

static __device__ __forceinline__ float bf2f(unsigned short u){
  union { unsigned int i; float f; } v; v.i = ((unsigned int)u) << 16; return v.f;
}
static __device__ __forceinline__ unsigned short f2bf(float f){
  union { float f; unsigned int i; } v; v.f = f;
  unsigned int x = v.i;
  return (unsigned short)((x + 0x7fffu + ((x >> 16) & 1u)) >> 16);
}

__device__ __forceinline__ void load_lds16(const void* g, void* l){
  __builtin_amdgcn_global_load_lds((const __attribute__((address_space(1))) void*)g,
                                   (__attribute__((address_space(3))) void*)l, 16, 0, 0);
}

// ---------------- edge preprocessing ----------------
__global__ void k_hist(const int* __restrict__ ei, const int* __restrict__ et, int* __restrict__ cnt){
  int e = blockIdx.x*256 + threadIdx.x;
  if (e < NEDGE){
    int key = ei[NEDGE + e]*NRELS + et[e];
    atomicAdd(&cnt[key], 1);
  }
}

// Disjoint contiguous ranges per segment (order-free): wave prefix + one atomic per wave.
__global__ void k_offsets(const int* __restrict__ cnt, int* __restrict__ offs, int* __restrict__ total){
  int i = blockIdx.x*256 + threadIdx.x;
  int lane = threadIdx.x & 63;
  int c = (i < NSEG) ? cnt[i] : 0;
  int inc = c;
  #pragma unroll
  for (int d=1; d<64; d<<=1){
    int v = __shfl_up(inc, d);
    if (lane >= d) inc += v;
  }
  __shared__ int wbase[4];
  if (lane == 63) wbase[threadIdx.x>>6] = atomicAdd(total, inc);
  __syncthreads();
  if (i < NSEG) offs[i] = wbase[threadIdx.x>>6] + inc - c;
}

__global__ void k_scatter(const int* __restrict__ ei, const int* __restrict__ et,
                          const int* __restrict__ offs, int* __restrict__ cursor, int* __restrict__ ssrc){
  int e = blockIdx.x*256 + threadIdx.x;
  if (e < NEDGE){
    int src = ei[e];
    int key = ei[NEDGE + e]*NRELS + et[e];
    int pos = offs[key] + atomicAdd(&cursor[key], 1);
    ssrc[pos] = src;
  }
}

// ---------------- segment means ----------------
// layer1: mean of node_x[src] (f32, 128 wide) per (dst,rel) -> s1 bf16 [MP][1024]
__global__ void k_agg1(const float* __restrict__ xin, const int* __restrict__ offs,
                       const int* __restrict__ cnt, const int* __restrict__ ssrc,
                       unsigned short* __restrict__ s1){
  int w = threadIdx.x >> 6, lane = threadIdx.x & 63;
  int seg = blockIdx.x*4 + w;
  if (seg >= NSEG) return;
  int c = cnt[seg], o = offs[seg];
  float a0 = 0.f, a1 = 0.f;
  for (int j=0;j<c;j++){
    int s = ssrc[o+j];
    float2 v = *(const float2*)(xin + (size_t)s*FEAT + lane*2);
    a0 += v.x; a1 += v.y;
  }
  float inv = (c > 0) ? 1.f/(float)c : 0.f;
  int n = seg >> 3, r = seg & 7;
  unsigned int pack = (unsigned int)f2bf(a0*inv) | ((unsigned int)f2bf(a1*inv) << 16);
  *(unsigned int*)(s1 + (size_t)n*1024 + r*FEAT + lane*2) = pack;
}

// layer2: mean of h[src] (bf16, 256 wide) per (dst,rel) -> s2 bf16 [MP][2048]
__global__ void k_agg2(const unsigned short* __restrict__ h, const int* __restrict__ offs,
                       const int* __restrict__ cnt, const int* __restrict__ ssrc,
                       unsigned short* __restrict__ s2){
  int w = threadIdx.x >> 6, lane = threadIdx.x & 63;
  int seg = blockIdx.x*4 + w;
  if (seg >= NSEG) return;
  int c = cnt[seg], o = offs[seg];
  float a0=0.f, a1=0.f, a2=0.f, a3=0.f;
  for (int j=0;j<c;j++){
    int s = ssrc[o+j];
    ushort4 v = *(const ushort4*)(h + (size_t)s*HID + lane*4);
    a0 += bf2f(v.x); a1 += bf2f(v.y); a2 += bf2f(v.z); a3 += bf2f(v.w);
  }
  float inv = (c > 0) ? 1.f/(float)c : 0.f;
  int n = seg >> 3, r = seg & 7;
  ushort4 out;
  out.x = f2bf(a0*inv); out.y = f2bf(a1*inv); out.z = f2bf(a2*inv); out.w = f2bf(a3*inv);
  *(ushort4*)(s2 + (size_t)n*2048 + r*HID + lane*4) = out;
}

// ---------------- weight prep ----------------
__global__ void k_cvt_nodex(const float* __restrict__ xin, unsigned short* __restrict__ xb){
  int i = blockIdx.x*256 + threadIdx.x;
  if (i < NNODE*FEAT) xb[i] = f2bf(xin[i]);
}

// B1t: [256][1152] bf16, row o: k<1024 -> W1[r=k>>7][i=k&127][o], else root1[k-1024][o]
__global__ void k_genB1(const float* __restrict__ comp, const float* __restrict__ basis,
                        const float* __restrict__ root, unsigned short* __restrict__ Bt){
  int idx = blockIdx.x*256 + threadIdx.x;
  if (idx >= 256*1152) return;
  int o = idx / 1152, k = idx % 1152;
  float v;
  if (k < 1024){
    int r = k >> 7, i = k & 127;
    v = 0.f;
    for (int b=0;b<4;b++) v += comp[r*4+b] * basis[((b*128)+i)*256 + o];
  } else {
    v = root[(k-1024)*256 + o];
  }
  Bt[(size_t)o*1152 + k] = f2bf(v);
}

// B2t: [128][2304] bf16
__global__ void k_genB2(const float* __restrict__ comp, const float* __restrict__ basis,
                        const float* __restrict__ root, unsigned short* __restrict__ Bt){
  int idx = blockIdx.x*256 + threadIdx.x;
  if (idx >= 128*2304) return;
  int o = idx / 2304, k = idx % 2304;
  float v;
  if (k < 2048){
    int r = k >> 8, i = k & 255;
    v = 0.f;
    for (int b=0;b<4;b++) v += comp[r*4+b] * basis[((b*256)+i)*128 + o];
  } else {
    v = root[(k-2048)*128 + o];
  }
  Bt[(size_t)o*2304 + k] = f2bf(v);
}

// ---------------- GEMM: C[M x 128tile] = [A0|A1] @ Bt^T ----------------
template<int BM, bool RELU>
__global__ __launch_bounds__(256, 2)
void k_gemm(const unsigned short* __restrict__ A0, int ldA0,
            const unsigned short* __restrict__ A1, int ldA1, int K0, int K,
            const unsigned short* __restrict__ Bt,
            const float* __restrict__ bias,
            unsigned short* __restrict__ Cb, float* __restrict__ Cf, int ldC)
{
  constexpr int BK = 64;
  constexpr int FM = BM/32;          // 16x16 m-frags per wave (2 wave-rows)
  constexpr int TA = BM*8/256;       // 16B chunks per thread for A tile
  __shared__ __align__(16) unsigned short As[BM*BK];
  __shared__ __align__(16) unsigned short Bs[128*BK];

  const int tid  = threadIdx.x;
  const int w    = tid >> 6, lane = tid & 63;
  const int wr   = w >> 1,  wc   = w & 1;
  const int m0   = blockIdx.x * BM;
  const int n0   = blockIdx.y * 128;

  const f32x4 zero4 = {0.f,0.f,0.f,0.f};
  f32x4 acc[FM][4];
  for (int i=0;i<FM;i++) for (int j=0;j<4;j++) acc[i][j] = zero4;

  const int nkt = K / BK;
  for (int kt=0; kt<nkt; ++kt){
    const int kb = kt*BK;
    // stage A (pre-swizzled source -> linear LDS)
    {
      const unsigned short* Ab; int ld, kk;
      if (kb < K0){ Ab = A0; ld = ldA0; kk = kb; } else { Ab = A1; ld = ldA1; kk = kb - K0; }
      #pragma unroll
      for (int t=0;t<TA;t++){
        int c = t*256 + tid;
        int row = c >> 3, slot = c & 7;
        int srcs = slot ^ (row & 7);
        const unsigned short* g = Ab + (size_t)(m0+row)*ld + kk + srcs*8;
        load_lds16(g, (char*)As + (t*256 + w*64)*16);
      }
    }
    // stage B
    {
      #pragma unroll
      for (int t=0;t<4;t++){
        int c = t*256 + tid;
        int row = c >> 3, slot = c & 7;
        int srcs = slot ^ (row & 7);
        const unsigned short* g = Bt + (size_t)(n0+row)*K + kb + srcs*8;
        load_lds16(g, (char*)Bs + (t*256 + w*64)*16);
      }
    }
    asm volatile("s_waitcnt vmcnt(0)" ::: "memory");
    __syncthreads();
    // compute
    #pragma unroll
    for (int kk=0; kk<2; ++kk){
      bf16x8 bfr[4];
      #pragma unroll
      for (int fn=0; fn<4; ++fn){
        int row  = wc*64 + fn*16 + (lane & 15);
        int slot = (kk*4 + (lane >> 4)) ^ (row & 7);
        bfr[fn] = *(const bf16x8*)(Bs + row*64 + slot*8);
      }
      #pragma unroll
      for (int fm=0; fm<FM; ++fm){
        int row  = wr*(BM/2) + fm*16 + (lane & 15);
        int slot = (kk*4 + (lane >> 4)) ^ (row & 7);
        bf16x8 afr = *(const bf16x8*)(As + row*64 + slot*8);
        #pragma unroll
        for (int fn=0; fn<4; ++fn){
          acc[fm][fn] = __builtin_amdgcn_mfma_f32_16x16x32_bf16(afr, bfr[fn], acc[fm][fn], 0, 0, 0);
        }
      }
    }
    __syncthreads();
  }
  // epilogue: C/D layout col=lane&15, row=(lane>>4)*4+q  (outputs padded to MP rows -> no guards)
  #pragma unroll
  for (int fm=0; fm<FM; ++fm){
    int rbase = m0 + wr*(BM/2) + fm*16 + (lane >> 4)*4;
    #pragma unroll
    for (int fn=0; fn<4; ++fn){
      int col = n0 + wc*64 + fn*16 + (lane & 15);
      float b = bias[col];
      #pragma unroll
      for (int q=0;q<4;q++){
        float v = acc[fm][fn][q] + b;
        int row = rbase + q;
        if constexpr (RELU){
          v = v > 0.f ? v : 0.f;
          Cb[(size_t)row*ldC + col] = f2bf(v);
        } else {
          Cf[(size_t)row*ldC + col] = v;
        }
      }
    }
  }
}

// ---------------- head ----------------
__global__ void k_me(const float* __restrict__ x, const float* __restrict__ mw,
                     const float* __restrict__ mb, float* __restrict__ me){
  int id = blockIdx.x*256 + threadIdx.x;
  if (id >= NGRAPH*EMB) return;
  int g = id >> 7, e = id & 127;
  float s = mb[e];
  for (int i=0;i<HID;i++) s += x[g*HID + i] * mw[i*EMB + e];
  me[id] = s;
}

__global__ void k_scores(const float* __restrict__ nemb, const float* __restrict__ me,
                         const int* __restrict__ batch, float* __restrict__ sc){
  int w = threadIdx.x >> 6, lane = threadIdx.x & 63;
  int n = blockIdx.x*4 + w;
  if (n >= NNODE) return;
  int g = batch[n];
  float2 v = *(const float2*)(nemb + (size_t)n*EMB + lane*2);
  float2 m = *(const float2*)(me + g*EMB + lane*2);
  float p = v.x*m.x + v.y*m.y;
  for (int d=32; d; d>>=1) p += __shfl_down(p, d);
  if (lane == 0) sc[n] = p;
}

__global__ void k_lsm(const float* __restrict__ sc, float* __restrict__ out){
  __shared__ float sb[1024];
  __shared__ float red[256];
  int g = blockIdx.x, t = threadIdx.x;
  float lm = -1e30f;
  for (int j=t; j<1024; j+=256){
    float v = (j < NPG) ? sc[g*NPG + j] : -1e30f;
    sb[j] = v; lm = fmaxf(lm, v);
  }
  red[t] = lm; __syncthreads();
  for (int off=128; off; off>>=1){ if (t < off) red[t] = fmaxf(red[t], red[t+off]); __syncthreads(); }
  float mx = red[0]; __syncthreads();
  float ls = 0.f;
  for (int j=t; j<1024; j+=256){ if (j < NPG) ls += expf(sb[j] - mx); }
  red[t] = ls; __syncthreads();
  for (int off=128; off; off>>=1){ if (t < off) red[t] += red[t+off]; __syncthreads(); }
  float lse = mx + logf(red[0]);
  for (int j=t; j<NPG; j+=256) out[g*NPG + j] = sb[j] - lse;
}

// ---------------- launch ----------------
extern "C" void kernel_launch(void* const* d_in, const int* in_sizes, int n_in,
                              void* d_out, int out_size, void* d_ws, size_t ws_size,
                              hipStream_t stream) {
  const float* x       = (const float*)d_in[0];
  const float* node_x  = (const float*)d_in[2];
  const int*   ei      = (const int*)d_in[3];
  const int*   et      = (const int*)d_in[4];
  const int*   batch   = (const int*)d_in[5];
  const float* comp1   = (const float*)d_in[7];
  const float* basis1  = (const float*)d_in[8];
  const float* root1   = (const float*)d_in[9];
  const float* bias1   = (const float*)d_in[10];
  const float* comp2   = (const float*)d_in[11];
  const float* basis2  = (const float*)d_in[12];
  const float* root2   = (const float*)d_in[13];
  const float* bias2   = (const float*)d_in[14];
  const float* msg_w   = (const float*)d_in[15];
  const float* msg_b   = (const float*)d_in[16];
  float* out = (float*)d_out;

  char* p = (char*)d_ws;
  size_t off = 0;
  auto alloc = [&](size_t bytes) -> char* {
    char* r = p + off;
    off += (bytes + 255) & ~(size_t)255;
    return r;
  };
  int*            cnt    = (int*)alloc(NSEG*4);
  int*            offs   = (int*)alloc(NSEG*4);
  int*            cursor = (int*)alloc(NSEG*4);
  int*            ssrc   = (int*)alloc(NEDGE*4);
  int*            total  = (int*)alloc(256);
  unsigned short* B1t    = (unsigned short*)alloc((size_t)256*1152*2);
  unsigned short* B2t    = (unsigned short*)alloc((size_t)128*2304*2);
  float*          me     = (float*)alloc(NGRAPH*EMB*4);
  unsigned short* xb     = (unsigned short*)alloc((size_t)MP*FEAT*2);
  unsigned short* s1     = (unsigned short*)alloc((size_t)MP*1024*2);
  unsigned short* h      = (unsigned short*)alloc((size_t)MP*HID*2);
  unsigned short* s2     = (unsigned short*)alloc((size_t)MP*2048*2);
  float*          nemb   = (float*)alloc((size_t)MP*EMB*4);
  float*          sc     = (float*)alloc(NNODE*4);

  hipMemsetAsync(cnt,    0, NSEG*4, stream);
  hipMemsetAsync(cursor, 0, NSEG*4, stream);
  hipMemsetAsync(total,  0, 256, stream);

  k_hist   <<<1250, 256, 0, stream>>>(ei, et, cnt);
  k_offsets<<<625, 256, 0, stream>>>(cnt, offs, total);
  k_scatter<<<1250, 256, 0, stream>>>(ei, et, offs, cursor, ssrc);

  k_cvt_nodex<<<10000, 256, 0, stream>>>(node_x, xb);
  k_genB1<<<1152, 256, 0, stream>>>(comp1, basis1, root1, B1t);
  k_genB2<<<1152, 256, 0, stream>>>(comp2, basis2, root2, B2t);
  k_me   <<<10, 256, 0, stream>>>(x, msg_w, msg_b, me);

  k_agg1<<<40000, 256, 0, stream>>>(node_x, offs, cnt, ssrc, s1);
  k_gemm<64, true><<<dim3(MP/64, 2), 256, 0, stream>>>(s1, 1024, xb, FEAT, 1024, 1152,
                                                       B1t, bias1, h, nullptr, HID);
  k_agg2<<<40000, 256, 0, stream>>>(h, offs, cnt, ssrc, s2);
  k_gemm<64, false><<<dim3(MP/64, 1), 256, 0, stream>>>(s2, 2048, h, HID, 2048, 2304,
                                                        B2t, bias2, nullptr, nemb, EMB);

  k_scores<<<5000, 256, 0, stream>>>(nemb, me, batch, sc);
  k_lsm   <<<NGRAPH, 256, 0, stream>>>(sc, out);
}

// Round 3
// 241.180 us; speedup vs baseline: 2.3706x; 1.1662x over previous
//
#include <hip/hip_runtime.h>
#include <hip/hip_bf16.h>

#define NEDGE 320000
#define NNODE 20000
#define MP    20096      // 157*128 padded rows
#define NRELS 8
#define NSEG  (NNODE*NRELS)   // 160000
#define FEAT  128
#define HID   256
#define EMB   128
#define NGRAPH 20
#define NPG   1000
#define NBASE 4

typedef __attribute__((ext_vector_type(4))) float f32x4;
typedef __attribute__((ext_vector_type(8))) __bf16 bf16x8;

static __device__ __forceinline__ float bf2f(unsigned short u){
  union { unsigned int i; float f; } v; v.i = ((unsigned int)u) << 16; return v.f;
}
static __device__ __forceinline__ unsigned short f2bf(float f){
  union { float f; unsigned int i; } v; v.f = f;
  unsigned int x = v.i;
  return (unsigned short)((x + 0x7fffu + ((x >> 16) & 1u)) >> 16);
}

__device__ __forceinline__ void load_lds16(const void* g, void* l){
  __builtin_amdgcn_global_load_lds((const __attribute__((address_space(1))) void*)g,
                                   (__attribute__((address_space(3))) void*)l, 16, 0, 0);
}

// ---------------- edge preprocessing ----------------
__global__ void k_hist(const int* __restrict__ ei, const int* __restrict__ et, int* __restrict__ cnt){
  int e = blockIdx.x*256 + threadIdx.x;
  if (e < NEDGE){
    int key = ei[NEDGE + e]*NRELS + et[e];
    atomicAdd(&cnt[key], 1);
  }
}

// Disjoint contiguous ranges per segment (order-free): wave prefix + one atomic per wave.
__global__ void k_offsets(const int* __restrict__ cnt, int* __restrict__ offs, int* __restrict__ total){
  int i = blockIdx.x*256 + threadIdx.x;
  int lane = threadIdx.x & 63;
  int c = (i < NSEG) ? cnt[i] : 0;
  int inc = c;
  #pragma unroll
  for (int d=1; d<64; d<<=1){
    int v = __shfl_up(inc, d);
    if (lane >= d) inc += v;
  }
  __shared__ int wbase[4];
  if (lane == 63) wbase[threadIdx.x>>6] = atomicAdd(total, inc);
  __syncthreads();
  if (i < NSEG) offs[i] = wbase[threadIdx.x>>6] + inc - c;
}

__global__ void k_scatter(const int* __restrict__ ei, const int* __restrict__ et,
                          const int* __restrict__ offs, int* __restrict__ cursor, int* __restrict__ ssrc){
  int e = blockIdx.x*256 + threadIdx.x;
  if (e < NEDGE){
    int src = ei[e];
    int key = ei[NEDGE + e]*NRELS + et[e];
    int pos = offs[key] + atomicAdd(&cursor[key], 1);
    ssrc[pos] = src;
  }
}

// ---------------- basis-space segment means ----------------
// layer1: u_b[n] = sum_r comp1[r,b] * mean_{edges->(n,r)} node_x[src]  -> s1 bf16 [MP][4*128]
__global__ void k_agg1(const float* __restrict__ xin, const int* __restrict__ offs,
                       const int* __restrict__ cnt, const int* __restrict__ ssrc,
                       const float* __restrict__ comp,
                       unsigned short* __restrict__ s1){
  int w = threadIdx.x >> 6, lane = threadIdx.x & 63;
  int n = blockIdx.x*4 + w;
  if (n >= NNODE) return;
  float u0[NBASE] = {0,0,0,0}, u1[NBASE] = {0,0,0,0};
  int base = n*NRELS;
  for (int r=0;r<NRELS;r++){
    int c = cnt[base+r];
    if (c == 0) continue;
    int o = offs[base+r];
    float a0 = 0.f, a1 = 0.f;
    for (int j=0;j<c;j++){
      int s = ssrc[o+j];
      float2 v = *(const float2*)(xin + (size_t)s*FEAT + lane*2);
      a0 += v.x; a1 += v.y;
    }
    float inv = 1.f/(float)c;
    #pragma unroll
    for (int b=0;b<NBASE;b++){
      float wg = comp[r*NBASE+b]*inv;
      u0[b] += wg*a0; u1[b] += wg*a1;
    }
  }
  #pragma unroll
  for (int b=0;b<NBASE;b++){
    unsigned int pack = (unsigned int)f2bf(u0[b]) | ((unsigned int)f2bf(u1[b]) << 16);
    *(unsigned int*)(s1 + (size_t)n*(NBASE*FEAT) + b*FEAT + lane*2) = pack;
  }
}

// layer2: u_b[n] = sum_r comp2[r,b] * mean h[src] (bf16, 256 wide) -> s2 bf16 [MP][4*256]
__global__ void k_agg2(const unsigned short* __restrict__ h, const int* __restrict__ offs,
                       const int* __restrict__ cnt, const int* __restrict__ ssrc,
                       const float* __restrict__ comp,
                       unsigned short* __restrict__ s2){
  int w = threadIdx.x >> 6, lane = threadIdx.x & 63;
  int n = blockIdx.x*4 + w;
  if (n >= NNODE) return;
  float u0[NBASE]={0,0,0,0}, u1[NBASE]={0,0,0,0}, u2[NBASE]={0,0,0,0}, u3[NBASE]={0,0,0,0};
  int base = n*NRELS;
  for (int r=0;r<NRELS;r++){
    int c = cnt[base+r];
    if (c == 0) continue;
    int o = offs[base+r];
    float a0=0.f, a1=0.f, a2=0.f, a3=0.f;
    for (int j=0;j<c;j++){
      int s = ssrc[o+j];
      ushort4 v = *(const ushort4*)(h + (size_t)s*HID + lane*4);
      a0 += bf2f(v.x); a1 += bf2f(v.y); a2 += bf2f(v.z); a3 += bf2f(v.w);
    }
    float inv = 1.f/(float)c;
    #pragma unroll
    for (int b=0;b<NBASE;b++){
      float wg = comp[r*NBASE+b]*inv;
      u0[b] += wg*a0; u1[b] += wg*a1; u2[b] += wg*a2; u3[b] += wg*a3;
    }
  }
  #pragma unroll
  for (int b=0;b<NBASE;b++){
    ushort4 o4;
    o4.x = f2bf(u0[b]); o4.y = f2bf(u1[b]); o4.z = f2bf(u2[b]); o4.w = f2bf(u3[b]);
    *(ushort4*)(s2 + (size_t)n*(NBASE*HID) + b*HID + lane*4) = o4;
  }
}

// ---------------- weight prep ----------------
__global__ void k_cvt_nodex(const float* __restrict__ xin, unsigned short* __restrict__ xb){
  int i = blockIdx.x*256 + threadIdx.x;
  if (i < NNODE*FEAT) xb[i] = f2bf(xin[i]);
}

// B1t: [256][640] bf16; k<512 -> basis1 flat[k*256+o], else root1[(k-512)*256+o]
__global__ void k_genB1(const float* __restrict__ basis, const float* __restrict__ root,
                        unsigned short* __restrict__ Bt){
  int idx = blockIdx.x*256 + threadIdx.x;
  if (idx >= 256*640) return;
  int o = idx / 640, k = idx % 640;
  float v = (k < 512) ? basis[(size_t)k*256 + o] : root[(size_t)(k-512)*256 + o];
  Bt[(size_t)o*640 + k] = f2bf(v);
}

// B2t: [128][1280] bf16; k<1024 -> basis2 flat[k*128+o], else root2[(k-1024)*128+o]
__global__ void k_genB2(const float* __restrict__ basis, const float* __restrict__ root,
                        unsigned short* __restrict__ Bt){
  int idx = blockIdx.x*256 + threadIdx.x;
  if (idx >= 128*1280) return;
  int o = idx / 1280, k = idx % 1280;
  float v = (k < 1024) ? basis[(size_t)k*128 + o] : root[(size_t)(k-1024)*128 + o];
  Bt[(size_t)o*1280 + k] = f2bf(v);
}

// ---------------- GEMM: C[M x 128tile] = [A0|A1] @ Bt^T ----------------
template<int BM, bool RELU>
__global__ __launch_bounds__(256, 2)
void k_gemm(const unsigned short* __restrict__ A0, int ldA0,
            const unsigned short* __restrict__ A1, int ldA1, int K0, int K,
            const unsigned short* __restrict__ Bt,
            const float* __restrict__ bias,
            unsigned short* __restrict__ Cb, float* __restrict__ Cf, int ldC)
{
  constexpr int BK = 64;
  constexpr int FM = BM/32;          // 16x16 m-frags per wave (2 wave-rows)
  constexpr int TA = BM*8/256;       // 16B chunks per thread for A tile
  __shared__ __align__(16) unsigned short As[BM*BK];
  __shared__ __align__(16) unsigned short Bs[128*BK];

  const int tid  = threadIdx.x;
  const int w    = tid >> 6, lane = tid & 63;
  const int wr   = w >> 1,  wc   = w & 1;
  const int m0   = blockIdx.x * BM;
  const int n0   = blockIdx.y * 128;

  const f32x4 zero4 = {0.f,0.f,0.f,0.f};
  f32x4 acc[FM][4];
  for (int i=0;i<FM;i++) for (int j=0;j<4;j++) acc[i][j] = zero4;

  const int nkt = K / BK;
  for (int kt=0; kt<nkt; ++kt){
    const int kb = kt*BK;
    // stage A (pre-swizzled source -> linear LDS)
    {
      const unsigned short* Ab; int ld, kk;
      if (kb < K0){ Ab = A0; ld = ldA0; kk = kb; } else { Ab = A1; ld = ldA1; kk = kb - K0; }
      #pragma unroll
      for (int t=0;t<TA;t++){
        int c = t*256 + tid;
        int row = c >> 3, slot = c & 7;
        int srcs = slot ^ (row & 7);
        const unsigned short* g = Ab + (size_t)(m0+row)*ld + kk + srcs*8;
        load_lds16(g, (char*)As + (t*256 + w*64)*16);
      }
    }
    // stage B
    {
      #pragma unroll
      for (int t=0;t<4;t++){
        int c = t*256 + tid;
        int row = c >> 3, slot = c & 7;
        int srcs = slot ^ (row & 7);
        const unsigned short* g = Bt + (size_t)(n0+row)*K + kb + srcs*8;
        load_lds16(g, (char*)Bs + (t*256 + w*64)*16);
      }
    }
    asm volatile("s_waitcnt vmcnt(0)" ::: "memory");
    __syncthreads();
    // compute
    #pragma unroll
    for (int kk=0; kk<2; ++kk){
      bf16x8 bfr[4];
      #pragma unroll
      for (int fn=0; fn<4; ++fn){
        int row  = wc*64 + fn*16 + (lane & 15);
        int slot = (kk*4 + (lane >> 4)) ^ (row & 7);
        bfr[fn] = *(const bf16x8*)(Bs + row*64 + slot*8);
      }
      #pragma unroll
      for (int fm=0; fm<FM; ++fm){
        int row  = wr*(BM/2) + fm*16 + (lane & 15);
        int slot = (kk*4 + (lane >> 4)) ^ (row & 7);
        bf16x8 afr = *(const bf16x8*)(As + row*64 + slot*8);
        #pragma unroll
        for (int fn=0; fn<4; ++fn){
          acc[fm][fn] = __builtin_amdgcn_mfma_f32_16x16x32_bf16(afr, bfr[fn], acc[fm][fn], 0, 0, 0);
        }
      }
    }
    __syncthreads();
  }
  // epilogue: C/D layout col=lane&15, row=(lane>>4)*4+q  (outputs padded to MP rows -> no guards)
  #pragma unroll
  for (int fm=0; fm<FM; ++fm){
    int rbase = m0 + wr*(BM/2) + fm*16 + (lane >> 4)*4;
    #pragma unroll
    for (int fn=0; fn<4; ++fn){
      int col = n0 + wc*64 + fn*16 + (lane & 15);
      float b = bias[col];
      #pragma unroll
      for (int q=0;q<4;q++){
        float v = acc[fm][fn][q] + b;
        int row = rbase + q;
        if constexpr (RELU){
          v = v > 0.f ? v : 0.f;
          Cb[(size_t)row*ldC + col] = f2bf(v);
        } else {
          Cf[(size_t)row*ldC + col] = v;
        }
      }
    }
  }
}

// ---------------- head ----------------
__global__ void k_me(const float* __restrict__ x, const float* __restrict__ mw,
                     const float* __restrict__ mb, float* __restrict__ me){
  int id = blockIdx.x*256 + threadIdx.x;
  if (id >= NGRAPH*EMB) return;
  int g = id >> 7, e = id & 127;
  float s = mb[e];
  for (int i=0;i<HID;i++) s += x[g*HID + i] * mw[i*EMB + e];
  me[id] = s;
}

__global__ void k_scores(const float* __restrict__ nemb, const float* __restrict__ me,
                         const int* __restrict__ batch, float* __restrict__ sc){
  int w = threadIdx.x >> 6, lane = threadIdx.x & 63;
  int n = blockIdx.x*4 + w;
  if (n >= NNODE) return;
  int g = batch[n];
  float2 v = *(const float2*)(nemb + (size_t)n*EMB + lane*2);
  float2 m = *(const float2*)(me + g*EMB + lane*2);
  float p = v.x*m.x + v.y*m.y;
  for (int d=32; d; d>>=1) p += __shfl_down(p, d);
  if (lane == 0) sc[n] = p;
}

__global__ void k_lsm(const float* __restrict__ sc, float* __restrict__ out){
  __shared__ float sb[1024];
  __shared__ float red[256];
  int g = blockIdx.x, t = threadIdx.x;
  float lm = -1e30f;
  for (int j=t; j<1024; j+=256){
    float v = (j < NPG) ? sc[g*NPG + j] : -1e30f;
    sb[j] = v; lm = fmaxf(lm, v);
  }
  red[t] = lm; __syncthreads();
  for (int off=128; off; off>>=1){ if (t < off) red[t] = fmaxf(red[t], red[t+off]); __syncthreads(); }
  float mx = red[0]; __syncthreads();
  float ls = 0.f;
  for (int j=t; j<1024; j+=256){ if (j < NPG) ls += expf(sb[j] - mx); }
  red[t] = ls; __syncthreads();
  for (int off=128; off; off>>=1){ if (t < off) red[t] += red[t+off]; __syncthreads(); }
  float lse = mx + logf(red[0]);
  for (int j=t; j<NPG; j+=256) out[g*NPG + j] = sb[j] - lse;
}

// ---------------- launch ----------------
extern "C" void kernel_launch(void* const* d_in, const int* in_sizes, int n_in,
                              void* d_out, int out_size, void* d_ws, size_t ws_size,
                              hipStream_t stream) {
  const float* x       = (const float*)d_in[0];
  const float* node_x  = (const float*)d_in[2];
  const int*   ei      = (const int*)d_in[3];
  const int*   et      = (const int*)d_in[4];
  const int*   batch   = (const int*)d_in[5];
  const float* comp1   = (const float*)d_in[7];
  const float* basis1  = (const float*)d_in[8];
  const float* root1   = (const float*)d_in[9];
  const float* bias1   = (const float*)d_in[10];
  const float* comp2   = (const float*)d_in[11];
  const float* basis2  = (const float*)d_in[12];
  const float* root2   = (const float*)d_in[13];
  const float* bias2   = (const float*)d_in[14];
  const float* msg_w   = (const float*)d_in[15];
  const float* msg_b   = (const float*)d_in[16];
  float* out = (float*)d_out;

  char* p = (char*)d_ws;
  size_t off = 0;
  auto alloc = [&](size_t bytes) -> char* {
    char* r = p + off;
    off += (bytes + 255) & ~(size_t)255;
    return r;
  };
  int*            cnt    = (int*)alloc(NSEG*4);
  int*            offs   = (int*)alloc(NSEG*4);
  int*            cursor = (int*)alloc(NSEG*4);
  int*            ssrc   = (int*)alloc(NEDGE*4);
  int*            total  = (int*)alloc(256);
  unsigned short* B1t    = (unsigned short*)alloc((size_t)256*640*2);
  unsigned short* B2t    = (unsigned short*)alloc((size_t)128*1280*2);
  float*          me     = (float*)alloc(NGRAPH*EMB*4);
  unsigned short* xb     = (unsigned short*)alloc((size_t)MP*FEAT*2);
  unsigned short* s1     = (unsigned short*)alloc((size_t)MP*512*2);
  unsigned short* h      = (unsigned short*)alloc((size_t)MP*HID*2);
  unsigned short* s2     = (unsigned short*)alloc((size_t)MP*1024*2);
  float*          nemb   = (float*)alloc((size_t)MP*EMB*4);
  float*          sc     = (float*)alloc(NNODE*4);

  hipMemsetAsync(cnt,    0, NSEG*4, stream);
  hipMemsetAsync(cursor, 0, NSEG*4, stream);
  hipMemsetAsync(total,  0, 256, stream);

  k_hist   <<<1250, 256, 0, stream>>>(ei, et, cnt);
  k_offsets<<<625, 256, 0, stream>>>(cnt, offs, total);
  k_scatter<<<1250, 256, 0, stream>>>(ei, et, offs, cursor, ssrc);

  k_cvt_nodex<<<10000, 256, 0, stream>>>(node_x, xb);
  k_genB1<<<640, 256, 0, stream>>>(basis1, root1, B1t);
  k_genB2<<<640, 256, 0, stream>>>(basis2, root2, B2t);
  k_me   <<<10, 256, 0, stream>>>(x, msg_w, msg_b, me);

  k_agg1<<<5000, 256, 0, stream>>>(node_x, offs, cnt, ssrc, comp1, s1);
  k_gemm<64, true><<<dim3(MP/64, 2), 256, 0, stream>>>(s1, 512, xb, FEAT, 512, 640,
                                                       B1t, bias1, h, nullptr, HID);
  k_agg2<<<5000, 256, 0, stream>>>(h, offs, cnt, ssrc, comp2, s2);
  k_gemm<32, false><<<dim3(MP/32, 1), 256, 0, stream>>>(s2, 1024, h, HID, 1024, 1280,
                                                        B2t, bias2, nullptr, nemb, EMB);

  k_scores<<<5000, 256, 0, stream>>>(nemb, me, batch, sc);
  k_lsm   <<<NGRAPH, 256, 0, stream>>>(sc, out);
}

// Round 4
// 186.772 us; speedup vs baseline: 3.0612x; 1.2913x over previous
//
#include <hip/hip_runtime.h>
#include <hip/hip_bf16.h>

#define NEDGE 320000
#define NNODE 20000
#define MP    20096      // 157*128 padded rows
#define NRELS 8
#define NSEG  (NNODE*NRELS)   // 160000
#define FEAT  128
#define HID   256
#define EMB   128
#define NGRAPH 20
#define NPG   1000
#define NBASE 4

typedef __attribute__((ext_vector_type(4))) float f32x4;
typedef __attribute__((ext_vector_type(8))) __bf16 bf16x8;

static __device__ __forceinline__ float bf2f(unsigned short u){
  union { unsigned int i; float f; } v; v.i = ((unsigned int)u) << 16; return v.f;
}
static __device__ __forceinline__ unsigned short f2bf(float f){
  union { float f; unsigned int i; } v; v.f = f;
  unsigned int x = v.i;
  return (unsigned short)((x + 0x7fffu + ((x >> 16) & 1u)) >> 16);
}

__device__ __forceinline__ void load_lds16(const void* g, void* l){
  __builtin_amdgcn_global_load_lds((const __attribute__((address_space(1))) void*)g,
                                   (__attribute__((address_space(3))) void*)l, 16, 0, 0);
}

// ---------------- edge preprocessing ----------------
__global__ void k_hist(const int* __restrict__ ei, const int* __restrict__ et, int* __restrict__ cnt){
  int e = blockIdx.x*256 + threadIdx.x;
  if (e < NEDGE){
    int key = ei[NEDGE + e]*NRELS + et[e];
    atomicAdd(&cnt[key], 1);
  }
}

// Disjoint contiguous ranges per segment: wave prefix + one atomic per wave.
// NOTE: within a wave (64 consecutive keys), ranges are contiguous & in key order,
// so the 8 segments of any node n (keys n*8..n*8+7) form ONE contiguous range.
__global__ void k_offsets(const int* __restrict__ cnt, int* __restrict__ offs, int* __restrict__ total){
  int i = blockIdx.x*256 + threadIdx.x;
  int lane = threadIdx.x & 63;
  int c = (i < NSEG) ? cnt[i] : 0;
  int inc = c;
  #pragma unroll
  for (int d=1; d<64; d<<=1){
    int v = __shfl_up(inc, d);
    if (lane >= d) inc += v;
  }
  __shared__ int wbase[4];
  if (lane == 63) wbase[threadIdx.x>>6] = atomicAdd(total, inc);
  __syncthreads();
  if (i < NSEG) offs[i] = wbase[threadIdx.x>>6] + inc - c;
}

// scatter sorted src + per-edge basis weights w_b = comp[r,b]/cnt(seg)
__global__ void k_scatter(const int* __restrict__ ei, const int* __restrict__ et,
                          const int* __restrict__ cnt, const int* __restrict__ offs,
                          int* __restrict__ cursor,
                          const float* __restrict__ comp1, const float* __restrict__ comp2,
                          int* __restrict__ ssrc, float4* __restrict__ wts1, float4* __restrict__ wts2){
  int e = blockIdx.x*256 + threadIdx.x;
  if (e < NEDGE){
    int src = ei[e];
    int r = et[e];
    int key = ei[NEDGE + e]*NRELS + r;
    int pos = offs[key] + atomicAdd(&cursor[key], 1);
    float inv = 1.f / (float)cnt[key];
    ssrc[pos] = src;
    float4 w1, w2;
    w1.x = comp1[r*4+0]*inv; w1.y = comp1[r*4+1]*inv; w1.z = comp1[r*4+2]*inv; w1.w = comp1[r*4+3]*inv;
    w2.x = comp2[r*4+0]*inv; w2.y = comp2[r*4+1]*inv; w2.z = comp2[r*4+2]*inv; w2.w = comp2[r*4+3]*inv;
    wts1[pos] = w1;
    wts2[pos] = w2;
  }
}

// ---------------- layer1 basis aggregation (flat edge loop, unroll 4) ----------------
// s1[n][b*128 + d] = sum_edges w1[b] * node_x[src][d]
__global__ void k_agg1(const float* __restrict__ xin, const int* __restrict__ offs,
                       const int* __restrict__ cnt, const int* __restrict__ ssrc,
                       const float4* __restrict__ wts,
                       unsigned short* __restrict__ s1){
  int w = threadIdx.x >> 6, lane = threadIdx.x & 63;
  int n = blockIdx.x*4 + w;
  if (n >= NNODE) return;
  int o0 = offs[n*NRELS];
  int C  = offs[n*NRELS+7] + cnt[n*NRELS+7] - o0;
  const int* sp = ssrc + o0;
  const float4* wp = wts + o0;
  float u0[NBASE] = {0,0,0,0}, u1[NBASE] = {0,0,0,0};
  int j = 0;
  for (; j+4 <= C; j += 4){
    int s0=sp[j], s1i=sp[j+1], s2i=sp[j+2], s3i=sp[j+3];
    float4 w0=wp[j], w1=wp[j+1], w2=wp[j+2], w3=wp[j+3];
    float2 v0 = *(const float2*)(xin + (size_t)s0*FEAT + lane*2);
    float2 v1 = *(const float2*)(xin + (size_t)s1i*FEAT + lane*2);
    float2 v2 = *(const float2*)(xin + (size_t)s2i*FEAT + lane*2);
    float2 v3 = *(const float2*)(xin + (size_t)s3i*FEAT + lane*2);
    #pragma unroll
    for (int b=0;b<NBASE;b++){
      float wb0=((const float*)&w0)[b], wb1=((const float*)&w1)[b];
      float wb2=((const float*)&w2)[b], wb3=((const float*)&w3)[b];
      u0[b] += wb0*v0.x + wb1*v1.x + wb2*v2.x + wb3*v3.x;
      u1[b] += wb0*v0.y + wb1*v1.y + wb2*v2.y + wb3*v3.y;
    }
  }
  for (; j < C; ++j){
    int s = sp[j];
    float4 wv = wp[j];
    float2 v = *(const float2*)(xin + (size_t)s*FEAT + lane*2);
    #pragma unroll
    for (int b=0;b<NBASE;b++){
      float wb = ((const float*)&wv)[b];
      u0[b] += wb*v.x; u1[b] += wb*v.y;
    }
  }
  #pragma unroll
  for (int b=0;b<NBASE;b++){
    unsigned int pack = (unsigned int)f2bf(u0[b]) | ((unsigned int)f2bf(u1[b]) << 16);
    *(unsigned int*)(s1 + (size_t)n*(NBASE*FEAT) + b*FEAT + lane*2) = pack;
  }
}

// ---------------- weight prep ----------------
__global__ void k_cvt_nodex(const float* __restrict__ xin, unsigned short* __restrict__ xb){
  int i = blockIdx.x*256 + threadIdx.x;
  if (i < NNODE*FEAT) xb[i] = f2bf(xin[i]);
}

// B1t: [256][640] bf16; k<512 -> basis1 flat[k*256+o], else root1[(k-512)*256+o]
__global__ void k_genB1(const float* __restrict__ basis, const float* __restrict__ root,
                        unsigned short* __restrict__ Bt){
  int idx = blockIdx.x*256 + threadIdx.x;
  if (idx >= 256*640) return;
  int o = idx / 640, k = idx % 640;
  float v = (k < 512) ? basis[(size_t)k*256 + o] : root[(size_t)(k-512)*256 + o];
  Bt[(size_t)o*640 + k] = f2bf(v);
}

// ---------------- GEMM: C[M x 128tile] = [A0|A1] @ Bt^T ----------------
template<int BM, bool RELU>
__global__ __launch_bounds__(256, 2)
void k_gemm(const unsigned short* __restrict__ A0, int ldA0,
            const unsigned short* __restrict__ A1, int ldA1, int K0, int K,
            const unsigned short* __restrict__ Bt,
            const float* __restrict__ bias,
            unsigned short* __restrict__ Cb, float* __restrict__ Cf, int ldC)
{
  constexpr int BK = 64;
  constexpr int FM = BM/32;
  constexpr int TA = BM*8/256;
  __shared__ __align__(16) unsigned short As[BM*BK];
  __shared__ __align__(16) unsigned short Bs[128*BK];

  const int tid  = threadIdx.x;
  const int w    = tid >> 6, lane = tid & 63;
  const int wr   = w >> 1,  wc   = w & 1;
  const int m0   = blockIdx.x * BM;
  const int n0   = blockIdx.y * 128;

  const f32x4 zero4 = {0.f,0.f,0.f,0.f};
  f32x4 acc[FM][4];
  for (int i=0;i<FM;i++) for (int j=0;j<4;j++) acc[i][j] = zero4;

  const int nkt = K / BK;
  for (int kt=0; kt<nkt; ++kt){
    const int kb = kt*BK;
    {
      const unsigned short* Ab; int ld, kk;
      if (kb < K0){ Ab = A0; ld = ldA0; kk = kb; } else { Ab = A1; ld = ldA1; kk = kb - K0; }
      #pragma unroll
      for (int t=0;t<TA;t++){
        int c = t*256 + tid;
        int row = c >> 3, slot = c & 7;
        int srcs = slot ^ (row & 7);
        const unsigned short* g = Ab + (size_t)(m0+row)*ld + kk + srcs*8;
        load_lds16(g, (char*)As + (t*256 + w*64)*16);
      }
    }
    {
      #pragma unroll
      for (int t=0;t<4;t++){
        int c = t*256 + tid;
        int row = c >> 3, slot = c & 7;
        int srcs = slot ^ (row & 7);
        const unsigned short* g = Bt + (size_t)(n0+row)*K + kb + srcs*8;
        load_lds16(g, (char*)Bs + (t*256 + w*64)*16);
      }
    }
    asm volatile("s_waitcnt vmcnt(0)" ::: "memory");
    __syncthreads();
    #pragma unroll
    for (int kk=0; kk<2; ++kk){
      bf16x8 bfr[4];
      #pragma unroll
      for (int fn=0; fn<4; ++fn){
        int row  = wc*64 + fn*16 + (lane & 15);
        int slot = (kk*4 + (lane >> 4)) ^ (row & 7);
        bfr[fn] = *(const bf16x8*)(Bs + row*64 + slot*8);
      }
      #pragma unroll
      for (int fm=0; fm<FM; ++fm){
        int row  = wr*(BM/2) + fm*16 + (lane & 15);
        int slot = (kk*4 + (lane >> 4)) ^ (row & 7);
        bf16x8 afr = *(const bf16x8*)(As + row*64 + slot*8);
        #pragma unroll
        for (int fn=0; fn<4; ++fn){
          acc[fm][fn] = __builtin_amdgcn_mfma_f32_16x16x32_bf16(afr, bfr[fn], acc[fm][fn], 0, 0, 0);
        }
      }
    }
    __syncthreads();
  }
  #pragma unroll
  for (int fm=0; fm<FM; ++fm){
    int rbase = m0 + wr*(BM/2) + fm*16 + (lane >> 4)*4;
    #pragma unroll
    for (int fn=0; fn<4; ++fn){
      int col = n0 + wc*64 + fn*16 + (lane & 15);
      float b = bias[col];
      #pragma unroll
      for (int q=0;q<4;q++){
        float v = acc[fm][fn][q] + b;
        int row = rbase + q;
        if constexpr (RELU){
          v = v > 0.f ? v : 0.f;
          Cb[(size_t)row*ldC + col] = f2bf(v);
        } else {
          Cf[(size_t)row*ldC + col] = v;
        }
      }
    }
  }
}

// ---------------- head ----------------
__global__ void k_me(const float* __restrict__ x, const float* __restrict__ mw,
                     const float* __restrict__ mb, float* __restrict__ me){
  int id = blockIdx.x*256 + threadIdx.x;
  if (id >= NGRAPH*EMB) return;
  int g = id >> 7, e = id & 127;
  float s = mb[e];
  for (int i=0;i<HID;i++) s += x[g*HID + i] * mw[i*EMB + e];
  me[id] = s;
}

// v[g][k] = dot(Bcat2[k,:], me[g,:]) ; Bcat2 = [basis2 (1024 rows) ; root2 (256 rows)], each row 128 wide
__global__ void k_v(const float* __restrict__ basis2, const float* __restrict__ root2,
                    const float* __restrict__ me, float* __restrict__ v){
  int w = threadIdx.x >> 6, lane = threadIdx.x & 63;
  int id = blockIdx.x*4 + w;
  if (id >= NGRAPH*1280) return;
  int g = id / 1280, k = id % 1280;
  const float* row = (k < 1024) ? (basis2 + (size_t)k*EMB) : (root2 + (size_t)(k-1024)*EMB);
  float2 a = *(const float2*)(row + lane*2);
  float2 m = *(const float2*)(me + g*EMB + lane*2);
  float p = a.x*m.x + a.y*m.y;
  #pragma unroll
  for (int d=32; d; d>>=1) p += __shfl_down(p, d);
  if (lane == 0) v[(size_t)g*1280 + k] = p;
}

// fused agg2+GEMM2+scores: score[n] = sum_e sum_b w2_e[b]*dot(h[src_e], v[g][b*256:]) + dot(h[n], v[g][1024:])
__global__ void k_score(const unsigned short* __restrict__ h, const int* __restrict__ offs,
                        const int* __restrict__ cnt, const int* __restrict__ ssrc,
                        const float4* __restrict__ wts, const float* __restrict__ v,
                        const int* __restrict__ batch, float* __restrict__ sc){
  int w = threadIdx.x >> 6, lane = threadIdx.x & 63;
  int n = blockIdx.x*4 + w;
  if (n >= NNODE) return;
  int g = batch[n];
  const float* vg = v + (size_t)g*1280;
  float4 vb[NBASE];
  #pragma unroll
  for (int b=0;b<NBASE;b++) vb[b] = *(const float4*)(vg + b*256 + lane*4);
  float4 vr = *(const float4*)(vg + 1024 + lane*4);

  int o0 = offs[n*NRELS];
  int C  = offs[n*NRELS+7] + cnt[n*NRELS+7] - o0;
  const int* sp = ssrc + o0;
  const float4* wp = wts + o0;
  float acc = 0.f;
  int j = 0;
  for (; j+4 <= C; j += 4){
    int s0=sp[j], s1i=sp[j+1], s2i=sp[j+2], s3i=sp[j+3];
    float4 w0=wp[j], w1=wp[j+1], w2=wp[j+2], w3=wp[j+3];
    ushort4 h0 = *(const ushort4*)(h + (size_t)s0*HID + lane*4);
    ushort4 h1 = *(const ushort4*)(h + (size_t)s1i*HID + lane*4);
    ushort4 h2 = *(const ushort4*)(h + (size_t)s2i*HID + lane*4);
    ushort4 h3 = *(const ushort4*)(h + (size_t)s3i*HID + lane*4);
    float x00=bf2f(h0.x), x01=bf2f(h0.y), x02=bf2f(h0.z), x03=bf2f(h0.w);
    float x10=bf2f(h1.x), x11=bf2f(h1.y), x12=bf2f(h1.z), x13=bf2f(h1.w);
    float x20=bf2f(h2.x), x21=bf2f(h2.y), x22=bf2f(h2.z), x23=bf2f(h2.w);
    float x30=bf2f(h3.x), x31=bf2f(h3.y), x32=bf2f(h3.z), x33=bf2f(h3.w);
    #pragma unroll
    for (int b=0;b<NBASE;b++){
      float p0 = x00*vb[b].x + x01*vb[b].y + x02*vb[b].z + x03*vb[b].w;
      float p1 = x10*vb[b].x + x11*vb[b].y + x12*vb[b].z + x13*vb[b].w;
      float p2 = x20*vb[b].x + x21*vb[b].y + x22*vb[b].z + x23*vb[b].w;
      float p3 = x30*vb[b].x + x31*vb[b].y + x32*vb[b].z + x33*vb[b].w;
      acc += ((const float*)&w0)[b]*p0 + ((const float*)&w1)[b]*p1
           + ((const float*)&w2)[b]*p2 + ((const float*)&w3)[b]*p3;
    }
  }
  for (; j < C; ++j){
    int s = sp[j];
    float4 wv = wp[j];
    ushort4 hv = *(const ushort4*)(h + (size_t)s*HID + lane*4);
    float x0=bf2f(hv.x), x1=bf2f(hv.y), x2=bf2f(hv.z), x3=bf2f(hv.w);
    #pragma unroll
    for (int b=0;b<NBASE;b++){
      float p = x0*vb[b].x + x1*vb[b].y + x2*vb[b].z + x3*vb[b].w;
      acc += ((const float*)&wv)[b]*p;
    }
  }
  // root term (bias2 contributes a per-graph constant -> cancels in log_softmax)
  ushort4 hn = *(const ushort4*)(h + (size_t)n*HID + lane*4);
  acc += bf2f(hn.x)*vr.x + bf2f(hn.y)*vr.y + bf2f(hn.z)*vr.z + bf2f(hn.w)*vr.w;
  #pragma unroll
  for (int d=32; d; d>>=1) acc += __shfl_down(acc, d);
  if (lane == 0) sc[n] = acc;
}

__global__ void k_lsm(const float* __restrict__ sc, float* __restrict__ out){
  __shared__ float sb[1024];
  __shared__ float red[256];
  int g = blockIdx.x, t = threadIdx.x;
  float lm = -1e30f;
  for (int j=t; j<1024; j+=256){
    float v = (j < NPG) ? sc[g*NPG + j] : -1e30f;
    sb[j] = v; lm = fmaxf(lm, v);
  }
  red[t] = lm; __syncthreads();
  for (int off=128; off; off>>=1){ if (t < off) red[t] = fmaxf(red[t], red[t+off]); __syncthreads(); }
  float mx = red[0]; __syncthreads();
  float ls = 0.f;
  for (int j=t; j<1024; j+=256){ if (j < NPG) ls += expf(sb[j] - mx); }
  red[t] = ls; __syncthreads();
  for (int off=128; off; off>>=1){ if (t < off) red[t] += red[t+off]; __syncthreads(); }
  float lse = mx + logf(red[0]);
  for (int j=t; j<NPG; j+=256) out[g*NPG + j] = sb[j] - lse;
}

// ---------------- launch ----------------
extern "C" void kernel_launch(void* const* d_in, const int* in_sizes, int n_in,
                              void* d_out, int out_size, void* d_ws, size_t ws_size,
                              hipStream_t stream) {
  const float* x       = (const float*)d_in[0];
  const float* node_x  = (const float*)d_in[2];
  const int*   ei      = (const int*)d_in[3];
  const int*   et      = (const int*)d_in[4];
  const int*   batch   = (const int*)d_in[5];
  const float* comp1   = (const float*)d_in[7];
  const float* basis1  = (const float*)d_in[8];
  const float* root1   = (const float*)d_in[9];
  const float* bias1   = (const float*)d_in[10];
  const float* comp2   = (const float*)d_in[11];
  const float* basis2  = (const float*)d_in[12];
  const float* root2   = (const float*)d_in[13];
  const float* msg_w   = (const float*)d_in[15];
  const float* msg_b   = (const float*)d_in[16];
  float* out = (float*)d_out;

  char* p = (char*)d_ws;
  size_t off = 0;
  auto alloc = [&](size_t bytes) -> char* {
    char* r = p + off;
    off += (bytes + 255) & ~(size_t)255;
    return r;
  };
  int*            cnt    = (int*)alloc(NSEG*4);
  int*            offs   = (int*)alloc(NSEG*4);
  int*            cursor = (int*)alloc(NSEG*4);
  int*            ssrc   = (int*)alloc(NEDGE*4);
  float4*         wts1   = (float4*)alloc((size_t)NEDGE*16);
  float4*         wts2   = (float4*)alloc((size_t)NEDGE*16);
  int*            total  = (int*)alloc(256);
  unsigned short* B1t    = (unsigned short*)alloc((size_t)256*640*2);
  float*          me     = (float*)alloc(NGRAPH*EMB*4);
  float*          v      = (float*)alloc((size_t)NGRAPH*1280*4);
  unsigned short* xb     = (unsigned short*)alloc((size_t)MP*FEAT*2);
  unsigned short* s1     = (unsigned short*)alloc((size_t)MP*512*2);
  unsigned short* h      = (unsigned short*)alloc((size_t)MP*HID*2);
  float*          sc     = (float*)alloc(NNODE*4);

  hipMemsetAsync(cnt,    0, NSEG*4, stream);
  hipMemsetAsync(cursor, 0, NSEG*4, stream);
  hipMemsetAsync(total,  0, 256, stream);

  k_hist   <<<1250, 256, 0, stream>>>(ei, et, cnt);
  k_offsets<<<625, 256, 0, stream>>>(cnt, offs, total);
  k_scatter<<<1250, 256, 0, stream>>>(ei, et, cnt, offs, cursor, comp1, comp2, ssrc, wts1, wts2);

  k_cvt_nodex<<<10000, 256, 0, stream>>>(node_x, xb);
  k_genB1<<<640, 256, 0, stream>>>(basis1, root1, B1t);
  k_me <<<10, 256, 0, stream>>>(x, msg_w, msg_b, me);
  k_v  <<<6400, 256, 0, stream>>>(basis2, root2, me, v);

  k_agg1<<<5000, 256, 0, stream>>>(node_x, offs, cnt, ssrc, wts1, s1);
  k_gemm<64, true><<<dim3(MP/64, 2), 256, 0, stream>>>(s1, 512, xb, FEAT, 512, 640,
                                                       B1t, bias1, h, nullptr, HID);
  k_score<<<5000, 256, 0, stream>>>(h, offs, cnt, ssrc, wts2, v, batch, sc);
  k_lsm  <<<NGRAPH, 256, 0, stream>>>(sc, out);
}

// Round 5
// 184.362 us; speedup vs baseline: 3.1012x; 1.0131x over previous
//
#include <hip/hip_runtime.h>
#include <hip/hip_bf16.h>

#define NEDGE 320000
#define NNODE 20000
#define MP    20096      // 157*128 padded rows
#define NRELS 8
#define NSEG  (NNODE*NRELS)   // 160000
#define FEAT  128
#define HID   256
#define EMB   128
#define NGRAPH 20
#define NPG   1000
#define NBASE 4

typedef __attribute__((ext_vector_type(4))) float f32x4;
typedef __attribute__((ext_vector_type(8))) __bf16 bf16x8;

static __device__ __forceinline__ float bf2f(unsigned short u){
  union { unsigned int i; float f; } v; v.i = ((unsigned int)u) << 16; return v.f;
}
static __device__ __forceinline__ unsigned short f2bf(float f){
  union { float f; unsigned int i; } v; v.f = f;
  unsigned int x = v.i;
  return (unsigned short)((x + 0x7fffu + ((x >> 16) & 1u)) >> 16);
}

__device__ __forceinline__ void load_lds16(const void* g, void* l){
  __builtin_amdgcn_global_load_lds((const __attribute__((address_space(1))) void*)g,
                                   (__attribute__((address_space(3))) void*)l, 16, 0, 0);
}

// ---------------- init (replaces hipMemsetAsync: rocclr fill was 43us each in-graph) ----------------
__global__ void k_zero(int* __restrict__ cnt, int* __restrict__ total){
  int i = blockIdx.x*256 + threadIdx.x;
  if (i < NSEG) cnt[i] = 0;
  if (i == 0) *total = 0;
}

// ---------------- edge preprocessing ----------------
__global__ void k_hist(const int* __restrict__ ei, const int* __restrict__ et, int* __restrict__ cnt){
  int e = blockIdx.x*256 + threadIdx.x;
  if (e < NEDGE){
    int key = ei[NEDGE + e]*NRELS + et[e];
    atomicAdd(&cnt[key], 1);
  }
}

// Disjoint contiguous ranges per segment: wave prefix + one atomic per wave.
// Writes the range base into BOTH offs (stable copy) and cursor (bump-allocated by scatter).
// Within a wave (64 consecutive keys) ranges are contiguous & key-ordered, so the 8 segments
// of any node n form ONE contiguous range.
__global__ void k_offsets(const int* __restrict__ cnt, int* __restrict__ offs,
                          int* __restrict__ cursor, int* __restrict__ total){
  int i = blockIdx.x*256 + threadIdx.x;
  int lane = threadIdx.x & 63;
  int c = (i < NSEG) ? cnt[i] : 0;
  int inc = c;
  #pragma unroll
  for (int d=1; d<64; d<<=1){
    int v = __shfl_up(inc, d);
    if (lane >= d) inc += v;
  }
  __shared__ int wbase[4];
  if (lane == 63) wbase[threadIdx.x>>6] = atomicAdd(total, inc);
  __syncthreads();
  if (i < NSEG){
    int base = wbase[threadIdx.x>>6] + inc - c;
    offs[i] = base;
    cursor[i] = base;
  }
}

// scatter sorted src + per-edge basis weights w_b = comp[r,b]/cnt(seg)
__global__ void k_scatter(const int* __restrict__ ei, const int* __restrict__ et,
                          const int* __restrict__ cnt, int* __restrict__ cursor,
                          const float* __restrict__ comp1, const float* __restrict__ comp2,
                          int* __restrict__ ssrc, float4* __restrict__ wts1, float4* __restrict__ wts2){
  int e = blockIdx.x*256 + threadIdx.x;
  if (e < NEDGE){
    int src = ei[e];
    int r = et[e];
    int key = ei[NEDGE + e]*NRELS + r;
    int pos = atomicAdd(&cursor[key], 1);
    float inv = 1.f / (float)cnt[key];
    ssrc[pos] = src;
    float4 w1, w2;
    w1.x = comp1[r*4+0]*inv; w1.y = comp1[r*4+1]*inv; w1.z = comp1[r*4+2]*inv; w1.w = comp1[r*4+3]*inv;
    w2.x = comp2[r*4+0]*inv; w2.y = comp2[r*4+1]*inv; w2.z = comp2[r*4+2]*inv; w2.w = comp2[r*4+3]*inv;
    wts1[pos] = w1;
    wts2[pos] = w2;
  }
}

// ---------------- layer1 basis aggregation (flat edge loop, unroll 4) ----------------
// s1[n][b*128 + d] = sum_edges w1[b] * node_x[src][d]
__global__ void k_agg1(const float* __restrict__ xin, const int* __restrict__ offs,
                       const int* __restrict__ cnt, const int* __restrict__ ssrc,
                       const float4* __restrict__ wts,
                       unsigned short* __restrict__ s1){
  int w = threadIdx.x >> 6, lane = threadIdx.x & 63;
  int n = blockIdx.x*4 + w;
  if (n >= NNODE) return;
  int o0 = offs[n*NRELS];
  int C  = offs[n*NRELS+7] + cnt[n*NRELS+7] - o0;
  const int* sp = ssrc + o0;
  const float4* wp = wts + o0;
  float u0[NBASE] = {0,0,0,0}, u1[NBASE] = {0,0,0,0};
  int j = 0;
  for (; j+4 <= C; j += 4){
    int s0=sp[j], s1i=sp[j+1], s2i=sp[j+2], s3i=sp[j+3];
    float4 w0=wp[j], w1=wp[j+1], w2=wp[j+2], w3=wp[j+3];
    float2 v0 = *(const float2*)(xin + (size_t)s0*FEAT + lane*2);
    float2 v1 = *(const float2*)(xin + (size_t)s1i*FEAT + lane*2);
    float2 v2 = *(const float2*)(xin + (size_t)s2i*FEAT + lane*2);
    float2 v3 = *(const float2*)(xin + (size_t)s3i*FEAT + lane*2);
    #pragma unroll
    for (int b=0;b<NBASE;b++){
      float wb0=((const float*)&w0)[b], wb1=((const float*)&w1)[b];
      float wb2=((const float*)&w2)[b], wb3=((const float*)&w3)[b];
      u0[b] += wb0*v0.x + wb1*v1.x + wb2*v2.x + wb3*v3.x;
      u1[b] += wb0*v0.y + wb1*v1.y + wb2*v2.y + wb3*v3.y;
    }
  }
  for (; j < C; ++j){
    int s = sp[j];
    float4 wv = wp[j];
    float2 v = *(const float2*)(xin + (size_t)s*FEAT + lane*2);
    #pragma unroll
    for (int b=0;b<NBASE;b++){
      float wb = ((const float*)&wv)[b];
      u0[b] += wb*v.x; u1[b] += wb*v.y;
    }
  }
  #pragma unroll
  for (int b=0;b<NBASE;b++){
    unsigned int pack = (unsigned int)f2bf(u0[b]) | ((unsigned int)f2bf(u1[b]) << 16);
    *(unsigned int*)(s1 + (size_t)n*(NBASE*FEAT) + b*FEAT + lane*2) = pack;
  }
}

// ---------------- weight prep ----------------
__global__ void k_cvt_nodex(const float* __restrict__ xin, unsigned short* __restrict__ xb){
  int i = blockIdx.x*256 + threadIdx.x;
  if (i < NNODE*FEAT) xb[i] = f2bf(xin[i]);
}

// B1t: [256][640] bf16; k<512 -> basis1 flat[k*256+o], else root1[(k-512)*256+o]
__global__ void k_genB1(const float* __restrict__ basis, const float* __restrict__ root,
                        unsigned short* __restrict__ Bt){
  int idx = blockIdx.x*256 + threadIdx.x;
  if (idx >= 256*640) return;
  int o = idx / 640, k = idx % 640;
  float v = (k < 512) ? basis[(size_t)k*256 + o] : root[(size_t)(k-512)*256 + o];
  Bt[(size_t)o*640 + k] = f2bf(v);
}

// ---------------- GEMM: C[M x 128tile] = [A0|A1] @ Bt^T ----------------
template<int BM, bool RELU>
__global__ __launch_bounds__(256, 2)
void k_gemm(const unsigned short* __restrict__ A0, int ldA0,
            const unsigned short* __restrict__ A1, int ldA1, int K0, int K,
            const unsigned short* __restrict__ Bt,
            const float* __restrict__ bias,
            unsigned short* __restrict__ Cb, float* __restrict__ Cf, int ldC)
{
  constexpr int BK = 64;
  constexpr int FM = BM/32;
  constexpr int TA = BM*8/256;
  __shared__ __align__(16) unsigned short As[BM*BK];
  __shared__ __align__(16) unsigned short Bs[128*BK];

  const int tid  = threadIdx.x;
  const int w    = tid >> 6, lane = tid & 63;
  const int wr   = w >> 1,  wc   = w & 1;
  const int m0   = blockIdx.x * BM;
  const int n0   = blockIdx.y * 128;

  const f32x4 zero4 = {0.f,0.f,0.f,0.f};
  f32x4 acc[FM][4];
  for (int i=0;i<FM;i++) for (int j=0;j<4;j++) acc[i][j] = zero4;

  const int nkt = K / BK;
  for (int kt=0; kt<nkt; ++kt){
    const int kb = kt*BK;
    {
      const unsigned short* Ab; int ld, kk;
      if (kb < K0){ Ab = A0; ld = ldA0; kk = kb; } else { Ab = A1; ld = ldA1; kk = kb - K0; }
      #pragma unroll
      for (int t=0;t<TA;t++){
        int c = t*256 + tid;
        int row = c >> 3, slot = c & 7;
        int srcs = slot ^ (row & 7);
        const unsigned short* g = Ab + (size_t)(m0+row)*ld + kk + srcs*8;
        load_lds16(g, (char*)As + (t*256 + w*64)*16);
      }
    }
    {
      #pragma unroll
      for (int t=0;t<4;t++){
        int c = t*256 + tid;
        int row = c >> 3, slot = c & 7;
        int srcs = slot ^ (row & 7);
        const unsigned short* g = Bt + (size_t)(n0+row)*K + kb + srcs*8;
        load_lds16(g, (char*)Bs + (t*256 + w*64)*16);
      }
    }
    asm volatile("s_waitcnt vmcnt(0)" ::: "memory");
    __syncthreads();
    #pragma unroll
    for (int kk=0; kk<2; ++kk){
      bf16x8 bfr[4];
      #pragma unroll
      for (int fn=0; fn<4; ++fn){
        int row  = wc*64 + fn*16 + (lane & 15);
        int slot = (kk*4 + (lane >> 4)) ^ (row & 7);
        bfr[fn] = *(const bf16x8*)(Bs + row*64 + slot*8);
      }
      #pragma unroll
      for (int fm=0; fm<FM; ++fm){
        int row  = wr*(BM/2) + fm*16 + (lane & 15);
        int slot = (kk*4 + (lane >> 4)) ^ (row & 7);
        bf16x8 afr = *(const bf16x8*)(As + row*64 + slot*8);
        #pragma unroll
        for (int fn=0; fn<4; ++fn){
          acc[fm][fn] = __builtin_amdgcn_mfma_f32_16x16x32_bf16(afr, bfr[fn], acc[fm][fn], 0, 0, 0);
        }
      }
    }
    __syncthreads();
  }
  #pragma unroll
  for (int fm=0; fm<FM; ++fm){
    int rbase = m0 + wr*(BM/2) + fm*16 + (lane >> 4)*4;
    #pragma unroll
    for (int fn=0; fn<4; ++fn){
      int col = n0 + wc*64 + fn*16 + (lane & 15);
      float b = bias[col];
      #pragma unroll
      for (int q=0;q<4;q++){
        float v = acc[fm][fn][q] + b;
        int row = rbase + q;
        if constexpr (RELU){
          v = v > 0.f ? v : 0.f;
          Cb[(size_t)row*ldC + col] = f2bf(v);
        } else {
          Cf[(size_t)row*ldC + col] = v;
        }
      }
    }
  }
}

// ---------------- head ----------------
__global__ void k_me(const float* __restrict__ x, const float* __restrict__ mw,
                     const float* __restrict__ mb, float* __restrict__ me){
  int id = blockIdx.x*256 + threadIdx.x;
  if (id >= NGRAPH*EMB) return;
  int g = id >> 7, e = id & 127;
  float s = mb[e];
  for (int i=0;i<HID;i++) s += x[g*HID + i] * mw[i*EMB + e];
  me[id] = s;
}

// v[g][k] = dot(Bcat2[k,:], me[g,:]) ; Bcat2 = [basis2 (1024 rows) ; root2 (256 rows)], each row 128 wide
__global__ void k_v(const float* __restrict__ basis2, const float* __restrict__ root2,
                    const float* __restrict__ me, float* __restrict__ v){
  int w = threadIdx.x >> 6, lane = threadIdx.x & 63;
  int id = blockIdx.x*4 + w;
  if (id >= NGRAPH*1280) return;
  int g = id / 1280, k = id % 1280;
  const float* row = (k < 1024) ? (basis2 + (size_t)k*EMB) : (root2 + (size_t)(k-1024)*EMB);
  float2 a = *(const float2*)(row + lane*2);
  float2 m = *(const float2*)(me + g*EMB + lane*2);
  float p = a.x*m.x + a.y*m.y;
  #pragma unroll
  for (int d=32; d; d>>=1) p += __shfl_down(p, d);
  if (lane == 0) v[(size_t)g*1280 + k] = p;
}

// fused agg2+GEMM2+scores: score[n] = sum_e sum_b w2_e[b]*dot(h[src_e], v[g][b*256:]) + dot(h[n], v[g][1024:])
__global__ void k_score(const unsigned short* __restrict__ h, const int* __restrict__ offs,
                        const int* __restrict__ cnt, const int* __restrict__ ssrc,
                        const float4* __restrict__ wts, const float* __restrict__ v,
                        const int* __restrict__ batch, float* __restrict__ sc){
  int w = threadIdx.x >> 6, lane = threadIdx.x & 63;
  int n = blockIdx.x*4 + w;
  if (n >= NNODE) return;
  int g = batch[n];
  const float* vg = v + (size_t)g*1280;
  float4 vb[NBASE];
  #pragma unroll
  for (int b=0;b<NBASE;b++) vb[b] = *(const float4*)(vg + b*256 + lane*4);
  float4 vr = *(const float4*)(vg + 1024 + lane*4);

  int o0 = offs[n*NRELS];
  int C  = offs[n*NRELS+7] + cnt[n*NRELS+7] - o0;
  const int* sp = ssrc + o0;
  const float4* wp = wts + o0;
  float acc = 0.f;
  int j = 0;
  for (; j+4 <= C; j += 4){
    int s0=sp[j], s1i=sp[j+1], s2i=sp[j+2], s3i=sp[j+3];
    float4 w0=wp[j], w1=wp[j+1], w2=wp[j+2], w3=wp[j+3];
    ushort4 h0 = *(const ushort4*)(h + (size_t)s0*HID + lane*4);
    ushort4 h1 = *(const ushort4*)(h + (size_t)s1i*HID + lane*4);
    ushort4 h2 = *(const ushort4*)(h + (size_t)s2i*HID + lane*4);
    ushort4 h3 = *(const ushort4*)(h + (size_t)s3i*HID + lane*4);
    float x00=bf2f(h0.x), x01=bf2f(h0.y), x02=bf2f(h0.z), x03=bf2f(h0.w);
    float x10=bf2f(h1.x), x11=bf2f(h1.y), x12=bf2f(h1.z), x13=bf2f(h1.w);
    float x20=bf2f(h2.x), x21=bf2f(h2.y), x22=bf2f(h2.z), x23=bf2f(h2.w);
    float x30=bf2f(h3.x), x31=bf2f(h3.y), x32=bf2f(h3.z), x33=bf2f(h3.w);
    #pragma unroll
    for (int b=0;b<NBASE;b++){
      float p0 = x00*vb[b].x + x01*vb[b].y + x02*vb[b].z + x03*vb[b].w;
      float p1 = x10*vb[b].x + x11*vb[b].y + x12*vb[b].z + x13*vb[b].w;
      float p2 = x20*vb[b].x + x21*vb[b].y + x22*vb[b].z + x23*vb[b].w;
      float p3 = x30*vb[b].x + x31*vb[b].y + x32*vb[b].z + x33*vb[b].w;
      acc += ((const float*)&w0)[b]*p0 + ((const float*)&w1)[b]*p1
           + ((const float*)&w2)[b]*p2 + ((const float*)&w3)[b]*p3;
    }
  }
  for (; j < C; ++j){
    int s = sp[j];
    float4 wv = wp[j];
    ushort4 hv = *(const ushort4*)(h + (size_t)s*HID + lane*4);
    float x0=bf2f(hv.x), x1=bf2f(hv.y), x2=bf2f(hv.z), x3=bf2f(hv.w);
    #pragma unroll
    for (int b=0;b<NBASE;b++){
      float p = x0*vb[b].x + x1*vb[b].y + x2*vb[b].z + x3*vb[b].w;
      acc += ((const float*)&wv)[b]*p;
    }
  }
  // root term (bias2 contributes a per-graph constant -> cancels in log_softmax)
  ushort4 hn = *(const ushort4*)(h + (size_t)n*HID + lane*4);
  acc += bf2f(hn.x)*vr.x + bf2f(hn.y)*vr.y + bf2f(hn.z)*vr.z + bf2f(hn.w)*vr.w;
  #pragma unroll
  for (int d=32; d; d>>=1) acc += __shfl_down(acc, d);
  if (lane == 0) sc[n] = acc;
}

__global__ void k_lsm(const float* __restrict__ sc, float* __restrict__ out){
  __shared__ float sb[1024];
  __shared__ float red[256];
  int g = blockIdx.x, t = threadIdx.x;
  float lm = -1e30f;
  for (int j=t; j<1024; j+=256){
    float v = (j < NPG) ? sc[g*NPG + j] : -1e30f;
    sb[j] = v; lm = fmaxf(lm, v);
  }
  red[t] = lm; __syncthreads();
  for (int off=128; off; off>>=1){ if (t < off) red[t] = fmaxf(red[t], red[t+off]); __syncthreads(); }
  float mx = red[0]; __syncthreads();
  float ls = 0.f;
  for (int j=t; j<1024; j+=256){ if (j < NPG) ls += expf(sb[j] - mx); }
  red[t] = ls; __syncthreads();
  for (int off=128; off; off>>=1){ if (t < off) red[t] += red[t+off]; __syncthreads(); }
  float lse = mx + logf(red[0]);
  for (int j=t; j<NPG; j+=256) out[g*NPG + j] = sb[j] - lse;
}

// ---------------- launch ----------------
extern "C" void kernel_launch(void* const* d_in, const int* in_sizes, int n_in,
                              void* d_out, int out_size, void* d_ws, size_t ws_size,
                              hipStream_t stream) {
  const float* x       = (const float*)d_in[0];
  const float* node_x  = (const float*)d_in[2];
  const int*   ei      = (const int*)d_in[3];
  const int*   et      = (const int*)d_in[4];
  const int*   batch   = (const int*)d_in[5];
  const float* comp1   = (const float*)d_in[7];
  const float* basis1  = (const float*)d_in[8];
  const float* root1   = (const float*)d_in[9];
  const float* bias1   = (const float*)d_in[10];
  const float* comp2   = (const float*)d_in[11];
  const float* basis2  = (const float*)d_in[12];
  const float* root2   = (const float*)d_in[13];
  const float* msg_w   = (const float*)d_in[15];
  const float* msg_b   = (const float*)d_in[16];
  float* out = (float*)d_out;

  char* p = (char*)d_ws;
  size_t off = 0;
  auto alloc = [&](size_t bytes) -> char* {
    char* r = p + off;
    off += (bytes + 255) & ~(size_t)255;
    return r;
  };
  int*            cnt    = (int*)alloc(NSEG*4);
  int*            offs   = (int*)alloc(NSEG*4);
  int*            cursor = (int*)alloc(NSEG*4);
  int*            ssrc   = (int*)alloc(NEDGE*4);
  float4*         wts1   = (float4*)alloc((size_t)NEDGE*16);
  float4*         wts2   = (float4*)alloc((size_t)NEDGE*16);
  int*            total  = (int*)alloc(256);
  unsigned short* B1t    = (unsigned short*)alloc((size_t)256*640*2);
  float*          me     = (float*)alloc(NGRAPH*EMB*4);
  float*          v      = (float*)alloc((size_t)NGRAPH*1280*4);
  unsigned short* xb     = (unsigned short*)alloc((size_t)MP*FEAT*2);
  unsigned short* s1     = (unsigned short*)alloc((size_t)MP*512*2);
  unsigned short* h      = (unsigned short*)alloc((size_t)MP*HID*2);
  float*          sc     = (float*)alloc(NNODE*4);

  k_zero   <<<625, 256, 0, stream>>>(cnt, total);
  k_hist   <<<1250, 256, 0, stream>>>(ei, et, cnt);
  k_offsets<<<625, 256, 0, stream>>>(cnt, offs, cursor, total);
  k_scatter<<<1250, 256, 0, stream>>>(ei, et, cnt, cursor, comp1, comp2, ssrc, wts1, wts2);

  k_cvt_nodex<<<10000, 256, 0, stream>>>(node_x, xb);
  k_genB1<<<640, 256, 0, stream>>>(basis1, root1, B1t);
  k_me <<<10, 256, 0, stream>>>(x, msg_w, msg_b, me);
  k_v  <<<6400, 256, 0, stream>>>(basis2, root2, me, v);

  k_agg1<<<5000, 256, 0, stream>>>(node_x, offs, cnt, ssrc, wts1, s1);
  k_gemm<64, true><<<dim3(MP/64, 2), 256, 0, stream>>>(s1, 512, xb, FEAT, 512, 640,
                                                       B1t, bias1, h, nullptr, HID);
  k_score<<<5000, 256, 0, stream>>>(h, offs, cnt, ssrc, wts2, v, batch, sc);
  k_lsm  <<<NGRAPH, 256, 0, stream>>>(sc, out);
}

// Round 6
// 158.779 us; speedup vs baseline: 3.6009x; 1.1611x over previous
//
#include <hip/hip_runtime.h>
#include <hip/hip_bf16.h>

#define NEDGE 320000
#define NNODE 20000
#define MP    20096      // 157*128 padded rows
#define NRELS 8
#define NSEG  (NNODE*NRELS)   // 160000
#define FEAT  128
#define HID   256
#define EMB   128
#define NGRAPH 20
#define NPG   1000
#define NBASE 4

typedef __attribute__((ext_vector_type(4))) float f32x4;
typedef __attribute__((ext_vector_type(8))) __bf16 bf16x8;

static __device__ __forceinline__ float bf2f(unsigned short u){
  union { unsigned int i; float f; } v; v.i = ((unsigned int)u) << 16; return v.f;
}
static __device__ __forceinline__ unsigned short f2bf(float f){
  union { float f; unsigned int i; } v; v.f = f;
  unsigned int x = v.i;
  return (unsigned short)((x + 0x7fffu + ((x >> 16) & 1u)) >> 16);
}

__device__ __forceinline__ void load_lds16(const void* g, void* l){
  __builtin_amdgcn_global_load_lds((const __attribute__((address_space(1))) void*)g,
                                   (__attribute__((address_space(3))) void*)l, 16, 0, 0);
}

// ---------------- init ----------------
__global__ void k_zero(int* __restrict__ cnt, int* __restrict__ total, float* __restrict__ zbias){
  int i = blockIdx.x*256 + threadIdx.x;
  if (i < NSEG) cnt[i] = 0;
  if (i < 128) zbias[i] = 0.f;
  if (i == 0) *total = 0;
}

// ---------------- edge preprocessing ----------------
__global__ void k_hist(const int* __restrict__ ei, const int* __restrict__ et, int* __restrict__ cnt){
  int e = blockIdx.x*256 + threadIdx.x;
  if (e < NEDGE){
    int key = ei[NEDGE + e]*NRELS + et[e];
    atomicAdd(&cnt[key], 1);
  }
}

// Disjoint contiguous ranges per segment: wave prefix + one atomic per wave.
// Within a wave (64 consecutive keys) ranges are contiguous & key-ordered, so the
// 8 segments of any node n form ONE contiguous range.
__global__ void k_offsets(const int* __restrict__ cnt, int* __restrict__ offs,
                          int* __restrict__ cursor, int* __restrict__ total){
  int i = blockIdx.x*256 + threadIdx.x;
  int lane = threadIdx.x & 63;
  int c = (i < NSEG) ? cnt[i] : 0;
  int inc = c;
  #pragma unroll
  for (int d=1; d<64; d<<=1){
    int v = __shfl_up(inc, d);
    if (lane >= d) inc += v;
  }
  __shared__ int wbase[4];
  if (lane == 63) wbase[threadIdx.x>>6] = atomicAdd(total, inc);
  __syncthreads();
  if (i < NSEG){
    int base = wbase[threadIdx.x>>6] + inc - c;
    offs[i] = base;
    cursor[i] = base;
  }
}

// scatter sorted src + per-edge basis weights w_b = comp[r,b]/cnt(seg)
__global__ void k_scatter(const int* __restrict__ ei, const int* __restrict__ et,
                          const int* __restrict__ cnt, int* __restrict__ cursor,
                          const float* __restrict__ comp1, const float* __restrict__ comp2,
                          int* __restrict__ ssrc, float4* __restrict__ wts1, float4* __restrict__ wts2){
  int e = blockIdx.x*256 + threadIdx.x;
  if (e < NEDGE){
    int src = ei[e];
    int r = et[e];
    int key = ei[NEDGE + e]*NRELS + r;
    int pos = atomicAdd(&cursor[key], 1);
    float inv = 1.f / (float)cnt[key];
    ssrc[pos] = src;
    float4 w1, w2;
    w1.x = comp1[r*4+0]*inv; w1.y = comp1[r*4+1]*inv; w1.z = comp1[r*4+2]*inv; w1.w = comp1[r*4+3]*inv;
    w2.x = comp2[r*4+0]*inv; w2.y = comp2[r*4+1]*inv; w2.z = comp2[r*4+2]*inv; w2.w = comp2[r*4+3]*inv;
    wts1[pos] = w1;
    wts2[pos] = w2;
  }
}

// ---------------- layer1 basis aggregation (bf16 gather, flat edge loop, unroll 4) ----------------
// s1[n][b*128 + d] = sum_edges w1[b] * xb[src][d]
__global__ void k_agg1(const unsigned short* __restrict__ xb, const int* __restrict__ offs,
                       const int* __restrict__ cnt, const int* __restrict__ ssrc,
                       const float4* __restrict__ wts,
                       unsigned short* __restrict__ s1){
  int w = threadIdx.x >> 6, lane = threadIdx.x & 63;
  int n = blockIdx.x*4 + w;
  if (n >= NNODE) return;
  int o0 = offs[n*NRELS];
  int C  = offs[n*NRELS+7] + cnt[n*NRELS+7] - o0;
  const int* sp = ssrc + o0;
  const float4* wp = wts + o0;
  float u0[NBASE] = {0,0,0,0}, u1[NBASE] = {0,0,0,0};
  int j = 0;
  for (; j+4 <= C; j += 4){
    int s0=sp[j], s1i=sp[j+1], s2i=sp[j+2], s3i=sp[j+3];
    float4 w0=wp[j], w1=wp[j+1], w2=wp[j+2], w3=wp[j+3];
    ushort2 v0 = *(const ushort2*)(xb + (size_t)s0*FEAT + lane*2);
    ushort2 v1 = *(const ushort2*)(xb + (size_t)s1i*FEAT + lane*2);
    ushort2 v2 = *(const ushort2*)(xb + (size_t)s2i*FEAT + lane*2);
    ushort2 v3 = *(const ushort2*)(xb + (size_t)s3i*FEAT + lane*2);
    float v0x=bf2f(v0.x), v0y=bf2f(v0.y), v1x=bf2f(v1.x), v1y=bf2f(v1.y);
    float v2x=bf2f(v2.x), v2y=bf2f(v2.y), v3x=bf2f(v3.x), v3y=bf2f(v3.y);
    #pragma unroll
    for (int b=0;b<NBASE;b++){
      float wb0=((const float*)&w0)[b], wb1=((const float*)&w1)[b];
      float wb2=((const float*)&w2)[b], wb3=((const float*)&w3)[b];
      u0[b] += wb0*v0x + wb1*v1x + wb2*v2x + wb3*v3x;
      u1[b] += wb0*v0y + wb1*v1y + wb2*v2y + wb3*v3y;
    }
  }
  for (; j < C; ++j){
    int s = sp[j];
    float4 wv = wp[j];
    ushort2 v = *(const ushort2*)(xb + (size_t)s*FEAT + lane*2);
    float vx=bf2f(v.x), vy=bf2f(v.y);
    #pragma unroll
    for (int b=0;b<NBASE;b++){
      float wb = ((const float*)&wv)[b];
      u0[b] += wb*vx; u1[b] += wb*vy;
    }
  }
  #pragma unroll
  for (int b=0;b<NBASE;b++){
    unsigned int pack = (unsigned int)f2bf(u0[b]) | ((unsigned int)f2bf(u1[b]) << 16);
    *(unsigned int*)(s1 + (size_t)n*(NBASE*FEAT) + b*FEAT + lane*2) = pack;
  }
}

// ---------------- weight prep ----------------
__global__ void k_cvt_nodex(const float* __restrict__ xin, unsigned short* __restrict__ xb){
  int i = blockIdx.x*256 + threadIdx.x;
  if (i < NNODE*FEAT) xb[i] = f2bf(xin[i]);
}

// B1t: [256][640] bf16; k<512 -> basis1 flat[k*256+o], else root1[(k-512)*256+o]
__global__ void k_genB1(const float* __restrict__ basis, const float* __restrict__ root,
                        unsigned short* __restrict__ Bt){
  int idx = blockIdx.x*256 + threadIdx.x;
  if (idx >= 256*640) return;
  int o = idx / 640, k = idx % 640;
  float v = (k < 512) ? basis[(size_t)k*256 + o] : root[(size_t)(k-512)*256 + o];
  Bt[(size_t)o*640 + k] = f2bf(v);
}

// ---------------- GEMM: C[M x 128tile] = [A0|A1] @ Bt^T ----------------
template<int BM, bool RELU>
__global__ __launch_bounds__(256, 2)
void k_gemm(const unsigned short* __restrict__ A0, int ldA0,
            const unsigned short* __restrict__ A1, int ldA1, int K0, int K,
            const unsigned short* __restrict__ Bt,
            const float* __restrict__ bias,
            unsigned short* __restrict__ Cb, float* __restrict__ Cf, int ldC)
{
  constexpr int BK = 64;
  constexpr int FM = BM/32;
  constexpr int TA = BM*8/256;
  __shared__ __align__(16) unsigned short As[BM*BK];
  __shared__ __align__(16) unsigned short Bs[128*BK];

  const int tid  = threadIdx.x;
  const int w    = tid >> 6, lane = tid & 63;
  const int wr   = w >> 1,  wc   = w & 1;
  const int m0   = blockIdx.x * BM;
  const int n0   = blockIdx.y * 128;

  const f32x4 zero4 = {0.f,0.f,0.f,0.f};
  f32x4 acc[FM][4];
  for (int i=0;i<FM;i++) for (int j=0;j<4;j++) acc[i][j] = zero4;

  const int nkt = K / BK;
  for (int kt=0; kt<nkt; ++kt){
    const int kb = kt*BK;
    {
      const unsigned short* Ab; int ld, kk;
      if (kb < K0){ Ab = A0; ld = ldA0; kk = kb; } else { Ab = A1; ld = ldA1; kk = kb - K0; }
      #pragma unroll
      for (int t=0;t<TA;t++){
        int c = t*256 + tid;
        int row = c >> 3, slot = c & 7;
        int srcs = slot ^ (row & 7);
        const unsigned short* g = Ab + (size_t)(m0+row)*ld + kk + srcs*8;
        load_lds16(g, (char*)As + (t*256 + w*64)*16);
      }
    }
    {
      #pragma unroll
      for (int t=0;t<4;t++){
        int c = t*256 + tid;
        int row = c >> 3, slot = c & 7;
        int srcs = slot ^ (row & 7);
        const unsigned short* g = Bt + (size_t)(n0+row)*K + kb + srcs*8;
        load_lds16(g, (char*)Bs + (t*256 + w*64)*16);
      }
    }
    asm volatile("s_waitcnt vmcnt(0)" ::: "memory");
    __syncthreads();
    #pragma unroll
    for (int kk=0; kk<2; ++kk){
      bf16x8 bfr[4];
      #pragma unroll
      for (int fn=0; fn<4; ++fn){
        int row  = wc*64 + fn*16 + (lane & 15);
        int slot = (kk*4 + (lane >> 4)) ^ (row & 7);
        bfr[fn] = *(const bf16x8*)(Bs + row*64 + slot*8);
      }
      #pragma unroll
      for (int fm=0; fm<FM; ++fm){
        int row  = wr*(BM/2) + fm*16 + (lane & 15);
        int slot = (kk*4 + (lane >> 4)) ^ (row & 7);
        bf16x8 afr = *(const bf16x8*)(As + row*64 + slot*8);
        #pragma unroll
        for (int fn=0; fn<4; ++fn){
          acc[fm][fn] = __builtin_amdgcn_mfma_f32_16x16x32_bf16(afr, bfr[fn], acc[fm][fn], 0, 0, 0);
        }
      }
    }
    __syncthreads();
  }
  #pragma unroll
  for (int fm=0; fm<FM; ++fm){
    int rbase = m0 + wr*(BM/2) + fm*16 + (lane >> 4)*4;
    #pragma unroll
    for (int fn=0; fn<4; ++fn){
      int col = n0 + wc*64 + fn*16 + (lane & 15);
      float b = bias[col];
      #pragma unroll
      for (int q=0;q<4;q++){
        float v = acc[fm][fn][q] + b;
        int row = rbase + q;
        if constexpr (RELU){
          v = v > 0.f ? v : 0.f;
          Cb[(size_t)row*ldC + col] = f2bf(v);
        } else {
          Cf[(size_t)row*ldC + col] = v;
        }
      }
    }
  }
}

// ---------------- head ----------------
__global__ void k_me(const float* __restrict__ x, const float* __restrict__ mw,
                     const float* __restrict__ mb, float* __restrict__ me){
  int id = blockIdx.x*256 + threadIdx.x;
  if (id >= NGRAPH*EMB) return;
  int g = id >> 7, e = id & 127;
  float s = mb[e];
  for (int i=0;i<HID;i++) s += x[g*HID + i] * mw[i*EMB + e];
  me[id] = s;
}

// v[g][k] = dot(Bcat2[k,:], me[g,:]) ; Bcat2 = [basis2 (1024 rows) ; root2 (256 rows)]
__global__ void k_v(const float* __restrict__ basis2, const float* __restrict__ root2,
                    const float* __restrict__ me, float* __restrict__ v){
  int w = threadIdx.x >> 6, lane = threadIdx.x & 63;
  int id = blockIdx.x*4 + w;
  if (id >= NGRAPH*1280) return;
  int g = id / 1280, k = id % 1280;
  const float* row = (k < 1024) ? (basis2 + (size_t)k*EMB) : (root2 + (size_t)(k-1024)*EMB);
  float2 a = *(const float2*)(row + lane*2);
  float2 m = *(const float2*)(me + g*EMB + lane*2);
  float p = a.x*m.x + a.y*m.y;
  #pragma unroll
  for (int d=32; d; d>>=1) p += __shfl_down(p, d);
  if (lane == 0) v[(size_t)g*1280 + k] = p;
}

// Bt_V [128 rows][256 cols] bf16: row c<80: (g=c/4,b=c&3) -> v[g][b*256+k];
// 80<=c<100: g=c-80 -> v[g][1024+k]; else 0.
__global__ void k_packV(const float* __restrict__ v, unsigned short* __restrict__ BtV){
  int idx = blockIdx.x*256 + threadIdx.x;
  if (idx >= 128*256) return;
  int c = idx >> 8, k = idx & 255;
  float val = 0.f;
  if (c < 80)        val = v[(size_t)(c>>2)*1280 + (c&3)*256 + k];
  else if (c < 100)  val = v[(size_t)(c-80)*1280 + 1024 + k];
  BtV[idx] = f2bf(val);
}

// score[n] = sum_e dot4(w2_e, D[src_e][4g..]) + D[n][80+g]   (one node per wave, one edge per lane)
__global__ void k_score2(const float* __restrict__ D, const int* __restrict__ offs,
                         const int* __restrict__ cnt, const int* __restrict__ ssrc,
                         const float4* __restrict__ wts, const int* __restrict__ batch,
                         float* __restrict__ sc){
  int w = threadIdx.x >> 6, lane = threadIdx.x & 63;
  int n = blockIdx.x*4 + w;
  if (n >= NNODE) return;
  int g = batch[n];
  int o0 = offs[n*NRELS];
  int C  = offs[n*NRELS+7] + cnt[n*NRELS+7] - o0;
  float acc = 0.f;
  for (int j = lane; j < C; j += 64){
    int s = ssrc[o0 + j];
    float4 wv = wts[o0 + j];
    float4 dv = *(const float4*)(D + (size_t)s*128 + g*4);
    acc += wv.x*dv.x + wv.y*dv.y + wv.z*dv.z + wv.w*dv.w;
  }
  #pragma unroll
  for (int d=32; d; d>>=1) acc += __shfl_down(acc, d);
  if (lane == 0) sc[n] = acc + D[(size_t)n*128 + 80 + g];
}

__global__ void k_lsm(const float* __restrict__ sc, float* __restrict__ out){
  __shared__ float sb[1024];
  __shared__ float red[256];
  int g = blockIdx.x, t = threadIdx.x;
  float lm = -1e30f;
  for (int j=t; j<1024; j+=256){
    float v = (j < NPG) ? sc[g*NPG + j] : -1e30f;
    sb[j] = v; lm = fmaxf(lm, v);
  }
  red[t] = lm; __syncthreads();
  for (int off=128; off; off>>=1){ if (t < off) red[t] = fmaxf(red[t], red[t+off]); __syncthreads(); }
  float mx = red[0]; __syncthreads();
  float ls = 0.f;
  for (int j=t; j<1024; j+=256){ if (j < NPG) ls += expf(sb[j] - mx); }
  red[t] = ls; __syncthreads();
  for (int off=128; off; off>>=1){ if (t < off) red[t] += red[t+off]; __syncthreads(); }
  float lse = mx + logf(red[0]);
  for (int j=t; j<NPG; j+=256) out[g*NPG + j] = sb[j] - lse;
}

// ---------------- launch ----------------
extern "C" void kernel_launch(void* const* d_in, const int* in_sizes, int n_in,
                              void* d_out, int out_size, void* d_ws, size_t ws_size,
                              hipStream_t stream) {
  const float* x       = (const float*)d_in[0];
  const float* node_x  = (const float*)d_in[2];
  const int*   ei      = (const int*)d_in[3];
  const int*   et      = (const int*)d_in[4];
  const int*   batch   = (const int*)d_in[5];
  const float* comp1   = (const float*)d_in[7];
  const float* basis1  = (const float*)d_in[8];
  const float* root1   = (const float*)d_in[9];
  const float* bias1   = (const float*)d_in[10];
  const float* comp2   = (const float*)d_in[11];
  const float* basis2  = (const float*)d_in[12];
  const float* root2   = (const float*)d_in[13];
  const float* msg_w   = (const float*)d_in[15];
  const float* msg_b   = (const float*)d_in[16];
  float* out = (float*)d_out;

  char* p = (char*)d_ws;
  size_t off = 0;
  auto alloc = [&](size_t bytes) -> char* {
    char* r = p + off;
    off += (bytes + 255) & ~(size_t)255;
    return r;
  };
  int*            cnt    = (int*)alloc(NSEG*4);
  int*            offs   = (int*)alloc(NSEG*4);
  int*            cursor = (int*)alloc(NSEG*4);
  int*            ssrc   = (int*)alloc(NEDGE*4);
  float4*         wts1   = (float4*)alloc((size_t)NEDGE*16);
  float4*         wts2   = (float4*)alloc((size_t)NEDGE*16);
  int*            total  = (int*)alloc(256);
  float*          zbias  = (float*)alloc(128*4);
  unsigned short* B1t    = (unsigned short*)alloc((size_t)256*640*2);
  unsigned short* BtV    = (unsigned short*)alloc((size_t)128*256*2);
  float*          me     = (float*)alloc(NGRAPH*EMB*4);
  float*          v      = (float*)alloc((size_t)NGRAPH*1280*4);
  unsigned short* xb     = (unsigned short*)alloc((size_t)MP*FEAT*2);
  unsigned short* s1     = (unsigned short*)alloc((size_t)MP*512*2);
  unsigned short* h      = (unsigned short*)alloc((size_t)MP*HID*2);
  float*          D      = (float*)alloc((size_t)MP*128*4);
  float*          sc     = (float*)alloc(NNODE*4);

  k_zero   <<<625, 256, 0, stream>>>(cnt, total, zbias);
  k_hist   <<<1250, 256, 0, stream>>>(ei, et, cnt);
  k_offsets<<<625, 256, 0, stream>>>(cnt, offs, cursor, total);
  k_scatter<<<1250, 256, 0, stream>>>(ei, et, cnt, cursor, comp1, comp2, ssrc, wts1, wts2);

  k_cvt_nodex<<<10000, 256, 0, stream>>>(node_x, xb);
  k_genB1<<<640, 256, 0, stream>>>(basis1, root1, B1t);
  k_me <<<10, 256, 0, stream>>>(x, msg_w, msg_b, me);
  k_v  <<<6400, 256, 0, stream>>>(basis2, root2, me, v);
  k_packV<<<128, 256, 0, stream>>>(v, BtV);

  k_agg1<<<5000, 256, 0, stream>>>(xb, offs, cnt, ssrc, wts1, s1);
  k_gemm<64, true><<<dim3(MP/64, 2), 256, 0, stream>>>(s1, 512, xb, FEAT, 512, 640,
                                                       B1t, bias1, h, nullptr, HID);
  k_gemm<64, false><<<dim3(MP/64, 1), 256, 0, stream>>>(h, HID, h, HID, HID, HID,
                                                        BtV, zbias, nullptr, D, 128);
  k_score2<<<5000, 256, 0, stream>>>(D, offs, cnt, ssrc, wts2, batch, sc);
  k_lsm  <<<NGRAPH, 256, 0, stream>>>(sc, out);
}